// Round 6
// baseline (2392.802 us; speedup 1.0000x reference)
//
#include <hip/hip_runtime.h>
#include <math.h>

typedef short s8v __attribute__((ext_vector_type(8)));
typedef __bf16 bf8 __attribute__((ext_vector_type(8)));
typedef float f4v __attribute__((ext_vector_type(4)));

#define DEV static __device__ __forceinline__

DEV ushort f2bf(float f){
  union { float f; unsigned u; } v; v.f = f;
  unsigned u = v.u;
  return (ushort)((u + 0x7fffu + ((u>>16)&1u)) >> 16);
}
DEV float bf2f(ushort u){
  union { unsigned u; float f; } v; v.u = ((unsigned)u)<<16; return v.f;
}
DEV float sigm(float x){ return 1.0f/(1.0f + __expf(-x)); }
DEV float tanh_(float x){ float e=__expf(2.f*x); return 1.f - 2.f/(e+1.f); }
DEV float wred(float x){
  #pragma unroll
  for(int off=32; off; off>>=1) x += __shfl_xor(x, off, 64);
  return x;
}
// swizzled LDS index for a [64][64]-ushort tile; uscol 8-aligned at use sites
DEV int swz(int row, int uscol){
  return (row<<6) + ((((uscol>>3) ^ (row&7))<<3) | (uscol&7));
}
DEV void gload16(const void* g, void* l){
  __builtin_amdgcn_global_load_lds((const __attribute__((address_space(1))) void*)g,
                                   (__attribute__((address_space(3))) void*)l, 16, 0, 0);
}
// gate-col permutation: n (= g*1024 + j) -> n' = (j>>4)*64 + g*16 + (j&15)
DEV int gperm(int n){
  return (((n&1023)>>4)<<6) | ((n>>10)<<4) | (n&15);
}

// ---------------- precompute kernels ----------------

__global__ void k_cast(const float* __restrict__ s, ushort* __restrict__ d, long n4){
  long i = (long)blockIdx.x*256 + threadIdx.x;
  const long st = (long)gridDim.x*256;
  for(; i<n4; i+=st){
    float4 v = ((const float4*)s)[i];
    ushort4 o; o.x=f2bf(v.x); o.y=f2bf(v.y); o.z=f2bf(v.z); o.w=f2bf(v.w);
    ((ushort4*)d)[i]=o;
  }
}

// merged transposes: src f32 [R][C] -> dst bf16 [C][ldd], dst[perm(n)][roff+k] = src[k][n]
__global__ __launch_bounds__(256) void k_tr7(const float* __restrict__ wih,
    const float* __restrict__ whh, const float* __restrict__ wtgt,
    const float* __restrict__ wcol, const float* __restrict__ wtab,
    const float* __restrict__ wact, ushort* __restrict__ WihT,
    ushort* __restrict__ WcatT, ushort* __restrict__ WtgtT, ushort* __restrict__ BcatT)
{
  __shared__ ushort T[64][72];
  const int bid = blockIdx.x;
  const float* src; ushort* dst; int C, ldd, roff, cx, ry; bool pm;
  if(bid < 2048){ src=wih; C=4096; dst=WihT; ldd=2048; roff=0; cx=bid&63; ry=bid>>6; pm=true; }
  else if(bid < 3072){ int j=bid-2048; src=wih+2048L*4096; C=4096; dst=WcatT; ldd=2048; roff=0; cx=j&63; ry=j>>6; pm=true; }
  else if(bid < 4096){ int j=bid-3072; src=whh; C=4096; dst=WcatT; ldd=2048; roff=1024; cx=j&63; ry=j>>6; pm=true; }
  else if(bid < 4352){ int j=bid-4096; src=wtgt; C=1024; dst=WtgtT; ldd=1024; roff=0; cx=j&15; ry=j>>4; pm=false; }
  else if(bid < 4608){ int j=bid-4352; src=wcol; C=1024; dst=BcatT; ldd=1024; roff=0; cx=j&15; ry=j>>4; pm=false; }
  else if(bid < 4864){ int j=bid-4608; src=wtab; C=1024; dst=BcatT+1048576; ldd=1024; roff=0; cx=j&15; ry=j>>4; pm=false; }
  else { int j=bid-4864; src=wact; C=1024; dst=BcatT+2097152; ldd=1024; roff=0; cx=j&15; ry=j>>4; pm=false; }
  const int c0 = cx<<6, r0 = ry<<6;
  const int tid = threadIdx.x;
  {
    const int rr = tid>>2, cc = (tid&3)<<4;
    const float* s = src + (long)(r0+rr)*C + c0 + cc;
    float4 v0=*(const float4*)(s), v1=*(const float4*)(s+4), v2=*(const float4*)(s+8), v3=*(const float4*)(s+12);
    ushort* t = &T[rr][cc];
    t[0]=f2bf(v0.x); t[1]=f2bf(v0.y); t[2]=f2bf(v0.z); t[3]=f2bf(v0.w);
    t[4]=f2bf(v1.x); t[5]=f2bf(v1.y); t[6]=f2bf(v1.z); t[7]=f2bf(v1.w);
    t[8]=f2bf(v2.x); t[9]=f2bf(v2.y); t[10]=f2bf(v2.z); t[11]=f2bf(v2.w);
    t[12]=f2bf(v3.x); t[13]=f2bf(v3.y); t[14]=f2bf(v3.z); t[15]=f2bf(v3.w);
  }
  __syncthreads();
  {
    const int rr = tid>>2, cc = (tid&3)<<4;
    s8v o0, o1;
    #pragma unroll
    for(int i=0;i<8;i++){ o0[i]=(short)T[cc+i][rr]; o1[i]=(short)T[cc+8+i][rr]; }
    const int n = c0 + rr;
    const int nr = pm ? gperm(n) : n;
    ushort* dp = dst + (long)nr*ldd + roff + r0 + cc;
    *(s8v*)dp = o0; *(s8v*)(dp+8) = o1;
  }
}

// P[2560][2048] bf16: cols 0:1024 = prev_emb(t), cols 1024:2048 = node_emb(t)
__global__ void k_gatherP(const float* __restrict__ emba, const float* __restrict__ ecol,
                          const float* __restrict__ etab, const float* __restrict__ symb,
                          const int* __restrict__ kindv, const int* __restrict__ gold,
                          const int* __restrict__ cur, ushort* __restrict__ P){
  long i = (long)blockIdx.x*256 + threadIdx.x;
  const long st = (long)gridDim.x*256;
  const long n4 = 2560L*2048/4;
  for(; i<n4; i+=st){
    long pos = i*4; int row = (int)(pos>>11); int col = (int)(pos&2047);
    int t = row>>6, b = row&63;
    ushort4 o;
    if(col < 1024){
      if(t==0){ o.x=o.y=o.z=o.w=0; *(ushort4*)&P[pos]=o; continue; }
      int k = kindv[(t-1)*64+b];
      int gi = gold[(t-1)*64+b];
      const float* s;
      if(k==0) s = emba + ((long)(gi & 127))*1024 + col;
      else if(k==1) s = ecol + (((long)b<<6) + (gi & 63))*1024 + col;
      else s = etab + (((long)b<<5) + (gi & 31))*1024 + col;
      float4 v = *(const float4*)s;
      o.x=f2bf(v.x); o.y=f2bf(v.y); o.z=f2bf(v.z); o.w=f2bf(v.w);
    } else {
      const float* s = symb + ((long)cur[t*64+b])*1024 + (col-1024);
      float4 v = *(const float4*)s;
      o.x=f2bf(v.x); o.y=f2bf(v.y); o.z=f2bf(v.z); o.w=f2bf(v.w);
    }
    *(ushort4*)&P[pos] = o;
  }
}

__global__ void k_init(const float* __restrict__ h0, const float* __restrict__ c0,
                       const float* __restrict__ bih, const float* __restrict__ bhh,
                       const int* __restrict__ smask,
                       float* __restrict__ cbuf, ushort* __restrict__ Ab0,
                       float* __restrict__ biasvec, float* __restrict__ sbias){
  int i = blockIdx.x*256 + threadIdx.x;
  if(i < 65536){
    cbuf[i]=c0[i];
    int row=i>>10, col=i&1023;
    Ab0[(row<<11)+1024+col]=f2bf(h0[i]);
  }
  if(i < 32768) sbias[i] = (smask[i]==1) ? -1.0e9f : 0.f;
  if(i < 4096){
    // biasvec stored in permuted layout n' : invert n' -> n
    int nt=i>>6, g=(i>>4)&3, j16=i&15;
    int n = (g<<10) | (nt<<4) | j16;
    biasvec[i] = bih[n] + bhh[n];
  }
}

__global__ void k_bias1(const float* __restrict__ bout,
                        const float* __restrict__ Wa, const float* __restrict__ ba,
                        const float* __restrict__ Wc, const float* __restrict__ bc,
                        const float* __restrict__ Wt, const float* __restrict__ bt,
                        float* __restrict__ vv){
  int j = blockIdx.x*256 + threadIdx.x;
  if(j >= 3072) return;
  int which = j>>10, col = j&1023;
  const float* W = (which==0)?Wa:(which==1)?Wc:Wt;
  const float* bb = (which==0)?ba:(which==1)?bc:bt;
  float s = bb[col];
  for(int i=0;i<1024;i++) s += bout[i]*W[((long)i<<10)+col];
  vv[j] = s;
}

__global__ void k_bias2a(const float* __restrict__ vv, const float* __restrict__ emb,
                         const float* __restrict__ ecol, const float* __restrict__ etab,
                         float* __restrict__ dbuf){
  int wid = blockIdx.x*4 + (threadIdx.x>>6);
  int l = threadIdx.x & 63;
  if(wid >= 6272) return;
  const float* src; const float* v;
  if(wid < 128){ src = emb + ((long)wid<<10); v = vv; }
  else if(wid < 4224){ src = ecol + ((long)(wid-128)<<10); v = vv+1024; }
  else { src = etab + ((long)(wid-4224)<<10); v = vv+2048; }
  const float* sp = src + l*16; const float* vp = v + l*16;
  float s = 0.f;
  #pragma unroll
  for(int i=0;i<16;i+=4){
    float4 a = *(const float4*)(sp+i); float4 bvv = *(const float4*)(vp+i);
    s += a.x*bvv.x + a.y*bvv.y + a.z*bvv.z + a.w*bvv.w;
  }
  s = wred(s);
  if(l==0) dbuf[wid] = s;
}

__global__ void k_bias2b(const float* __restrict__ dbuf,
                         const int* __restrict__ amask, const int* __restrict__ cmask,
                         const int* __restrict__ tmask,
                         float* __restrict__ ca, float* __restrict__ cb, float* __restrict__ ct){
  int i = blockIdx.x*256 + threadIdx.x;
  if(i < 8192){ ca[i] = dbuf[i&127] + ((amask[i]==1)?-1.0e9f:0.f); }
  else if(i < 12288){ int j=i-8192; cb[j] = dbuf[128+j] + ((cmask[j]==1)?-1.0e9f:0.f); }
  else if(i < 14336){ int j=i-12288; ct[j] = dbuf[4224+j] + ((tmask[j]==1)?-1.0e9f:0.f); }
}

// ---------------- 128x128 m97-style GEMM (global_load_lds, dbuf, swizzled) ----
// C[M,N] = A[M,K] @ B^T ; A [M][K] bf16, B [N][K] bf16. M%128==0, N%128==0, K%64==0.
// Bijective XCD swizzle on block id (m204).
template<bool OBF16, bool HASB>
__global__ __launch_bounds__(256,2) void k_gemm128(const ushort* __restrict__ Ap,
    const ushort* __restrict__ Bp, void* __restrict__ Cp, const float* __restrict__ bias,
    int N, int K)
{
  __shared__ __align__(16) ushort As[2][8192];
  __shared__ __align__(16) ushort Bs[2][8192];
  const int tid=threadIdx.x, w=tid>>6, l=tid&63;
  const int wr=w>>1, wc=w&1;
  const int nwg = gridDim.x*gridDim.y;
  const int orig = blockIdx.y*gridDim.x + blockIdx.x;
  const int xcd = orig & 7, qq = nwg>>3, rr_ = nwg&7;
  const int wgid = (xcd<rr_ ? xcd*(qq+1) : rr_*(qq+1)+(xcd-rr_)*qq) + (orig>>3);
  const int m0 = (wgid / gridDim.x)<<7, n0 = (wgid % gridDim.x)<<7;
  const int lr8 = l>>3, lc = l&7;
  f4v acc[4][4];
  #pragma unroll
  for(int m=0;m<4;m++)
    #pragma unroll
    for(int n=0;n<4;n++) acc[m][n]=(f4v){0.f,0.f,0.f,0.f};

  auto stage=[&](int buf, int k0){
    #pragma unroll
    for(int i=0;i<4;i++){
      const int rb = i*32 + w*8;
      const int row = rb + lr8;
      const int cp = (lc ^ (row&7))<<3;
      gload16(Ap + (long)(m0+row)*K + k0 + cp, &As[buf][rb<<6]);
      gload16(Bp + (long)(n0+row)*K + k0 + cp, &Bs[buf][rb<<6]);
    }
  };
  auto compute=[&](int buf){
    #pragma unroll
    for(int ks=0; ks<2; ks++){
      bf8 av[4], bv[4];
      #pragma unroll
      for(int m=0;m<4;m++){
        const int ar = wr*64 + (m<<4) + (l&15);
        const int ch = (ks<<2) + (l>>4);
        av[m] = *(const bf8*)&As[buf][(ar<<6) + ((ch ^ (ar&7))<<3)];
      }
      #pragma unroll
      for(int n=0;n<4;n++){
        const int br = wc*64 + (n<<4) + (l&15);
        const int ch = (ks<<2) + (l>>4);
        bv[n] = *(const bf8*)&Bs[buf][(br<<6) + ((ch ^ (br&7))<<3)];
      }
      #pragma unroll
      for(int m=0;m<4;m++)
        #pragma unroll
        for(int n=0;n<4;n++)
          acc[m][n] = __builtin_amdgcn_mfma_f32_16x16x32_bf16(av[m], bv[n], acc[m][n], 0,0,0);
    }
  };

  stage(0, 0);
  asm volatile("s_waitcnt vmcnt(0)" ::: "memory");
  __syncthreads();
  int cur=0;
  for(int k0=0;;){
    const int kn = k0+64;
    if(kn<K) stage(cur^1, kn);
    compute(cur);
    asm volatile("s_waitcnt vmcnt(0)" ::: "memory");
    __syncthreads();
    if(kn>=K) break;
    k0=kn; cur^=1;
  }
  #pragma unroll
  for(int m=0;m<4;m++){
    #pragma unroll
    for(int n=0;n<4;n++){
      const int col = n0 + wc*64 + (n<<4) + (l&15);
      float bv_ = 0.f;
      if constexpr(HASB) bv_ = bias[col];
      #pragma unroll
      for(int j=0;j<4;j++){
        const int row = m0 + wr*64 + (m<<4) + ((l>>4)<<2) + j;
        float v = acc[m][n][j] + bv_;
        if constexpr(OBF16) ((ushort*)Cp)[(long)row*N + col] = f2bf(v);
        else ((float*)Cp)[(long)row*N + col] = v;
      }
    }
  }
}

// ---------------- small-tile GEMM template (2-deep reg prefetch) ----------------
// C[M,N] = A[M,K] @ B ; B[k][n] = Bp[sBz*z + n*ldb + k]. K%128==0.
template<bool AF32, bool OBF16, bool HASB>
__global__ __launch_bounds__(256) void k_gemm(const void* __restrict__ Ap,
    const ushort* __restrict__ Bp, void* __restrict__ Cp, const float* __restrict__ bias,
    int M, int N, int K, int lda, int ldb, int ldc, long sAz, long sBz, long sCz)
{
  __shared__ __align__(16) ushort As[4096];
  __shared__ __align__(16) ushort Bs[4096];
  const int tid=threadIdx.x, w=tid>>6, l=tid&63, q4=l>>4;
  const int r=tid>>2, cc=(tid&3)<<4;
  const int m0=blockIdx.y<<6, n0=blockIdx.x<<6;
  const int z=blockIdx.z;
  f4v acc[4];
  #pragma unroll
  for(int i=0;i<4;i++) acc[i]=(f4v){0.f,0.f,0.f,0.f};

  struct PF { float4 f0,f1,f2,f3; s8v u0,u1,b0,b1; };
  PF pA, pB;

  auto loadAB=[&](int k0, PF& p){
    const int gm = m0 + r;
    if constexpr(AF32){
      if(gm < M){
        const float* a = (const float*)Ap + sAz*z + (long)gm*lda + k0 + cc;
        p.f0=*(const float4*)(a); p.f1=*(const float4*)(a+4); p.f2=*(const float4*)(a+8); p.f3=*(const float4*)(a+12);
      } else { p.f0=p.f1=p.f2=p.f3=make_float4(0.f,0.f,0.f,0.f); }
    } else {
      if(gm < M){
        const ushort* a = (const ushort*)Ap + sAz*z + (long)gm*lda + k0 + cc;
        p.u0=*(const s8v*)a; p.u1=*(const s8v*)(a+8);
      } else { p.u0=p.u1=(s8v){0,0,0,0,0,0,0,0}; }
    }
    const ushort* b = Bp + sBz*z + (long)(n0+r)*ldb + k0 + cc;
    p.b0=*(const s8v*)b; p.b1=*(const s8v*)(b+8);
  };
  auto stage=[&](const PF& p){
    s8v a0, a1;
    if constexpr(AF32){
      a0[0]=(short)f2bf(p.f0.x); a0[1]=(short)f2bf(p.f0.y); a0[2]=(short)f2bf(p.f0.z); a0[3]=(short)f2bf(p.f0.w);
      a0[4]=(short)f2bf(p.f1.x); a0[5]=(short)f2bf(p.f1.y); a0[6]=(short)f2bf(p.f1.z); a0[7]=(short)f2bf(p.f1.w);
      a1[0]=(short)f2bf(p.f2.x); a1[1]=(short)f2bf(p.f2.y); a1[2]=(short)f2bf(p.f2.z); a1[3]=(short)f2bf(p.f2.w);
      a1[4]=(short)f2bf(p.f3.x); a1[5]=(short)f2bf(p.f3.y); a1[6]=(short)f2bf(p.f3.z); a1[7]=(short)f2bf(p.f3.w);
    } else { a0=p.u0; a1=p.u1; }
    *(s8v*)&As[swz(r,cc)] = a0; *(s8v*)&As[swz(r,cc+8)] = a1;
    *(s8v*)&Bs[swz(r,cc)] = p.b0; *(s8v*)&Bs[swz(r,cc+8)] = p.b1;
  };
  auto compute=[&](){
    #pragma unroll
    for(int ks=0; ks<64; ks+=32){
      bf8 av = *(const bf8*)&As[swz((w<<4)+(l&15), ks+(q4<<3))];
      #pragma unroll
      for(int nf=0; nf<4; nf++){
        bf8 bv = *(const bf8*)&Bs[swz((nf<<4)+(l&15), ks+(q4<<3))];
        acc[nf] = __builtin_amdgcn_mfma_f32_16x16x32_bf16(av, bv, acc[nf], 0, 0, 0);
      }
    }
  };

  loadAB(0, pA); loadAB(64, pB);
  for(int k0=0; k0<K; k0+=128){
    stage(pA); __syncthreads();
    if(k0+128 < K) loadAB(k0+128, pA);
    compute(); __syncthreads();
    stage(pB); __syncthreads();
    if(k0+192 < K) loadAB(k0+192, pB);
    compute(); __syncthreads();
  }
  #pragma unroll
  for(int nf=0; nf<4; nf++){
    const int col = n0 + (nf<<4) + (l&15);
    float bv = 0.f;
    if constexpr(HASB) bv = bias[col];
    #pragma unroll
    for(int j=0;j<4;j++){
      const int row = m0 + (w<<4) + ((l>>4)<<2) + j;
      if(row < M){
        float v = acc[nf][j] + bv;
        if constexpr(OBF16) ((ushort*)Cp)[sCz*z + (long)row*ldc + col] = f2bf(v);
        else ((float*)Cp)[sCz*z + (long)row*ldc + col] = v;
      }
    }
  }
}

// ---------------- per-step small GEMM (global_load_lds + dbuf, 64x64 tile) -----
// M=64 fixed. A bf16 [64][lda]; B bf16 [N][ldb], block nt handles cols nt*64..+63.
// EPI==0: q writeout f32 + btgt bias. EPI==1: LSTM cell epilogue (permuted gates).
template<int EPI>
__global__ __launch_bounds__(256) void k_sgemm(
    const ushort* __restrict__ Ap, int lda,
    const ushort* __restrict__ Bp, int ldb, int K,
    const ushort* __restrict__ gpre_t, const float* __restrict__ cin,
    float* __restrict__ cout, ushort* __restrict__ AbOut, ushort* __restrict__ h2t,
    const float* __restrict__ btgt, float* __restrict__ qout)
{
  __shared__ __align__(16) ushort As[2][4096];
  __shared__ __align__(16) ushort Bs[2][4096];
  const int tid=threadIdx.x, w=tid>>6, l=tid&63, l15=l&15;
  const int lr8=l>>3, lc=l&7;
  const int nt=blockIdx.x;
  f4v acc[4];
  if constexpr(EPI==1){
    #pragma unroll
    for(int nf=0;nf<4;nf++){
      #pragma unroll
      for(int jj=0;jj<4;jj++){
        const int row=(w<<4)+((l>>4)<<2)+jj;
        acc[nf][jj]=bf2f(gpre_t[((long)row<<12)+(nt<<6)+(nf<<4)+l15]);
      }
    }
  } else {
    #pragma unroll
    for(int i=0;i<4;i++) acc[i]=(f4v){0.f,0.f,0.f,0.f};
  }
  auto stage=[&](int buf,int k0){
    #pragma unroll
    for(int i=0;i<2;i++){
      const int rb=i*32+w*8;
      const int row=rb+lr8;
      const int cp=(lc^(row&7))<<3;
      gload16(Ap + (long)row*lda + k0 + cp, &As[buf][rb<<6]);
      gload16(Bp + (long)((nt<<6)+row)*ldb + k0 + cp, &Bs[buf][rb<<6]);
    }
  };
  auto compute=[&](int buf){
    #pragma unroll
    for(int ks=0;ks<2;ks++){
      const int ch=(ks<<2)+(l>>4);
      const int ar=(w<<4)+l15;
      bf8 av = *(const bf8*)&As[buf][(ar<<6)+((ch^(ar&7))<<3)];
      #pragma unroll
      for(int nf=0;nf<4;nf++){
        const int br=(nf<<4)+l15;
        bf8 bv = *(const bf8*)&Bs[buf][(br<<6)+((ch^(br&7))<<3)];
        acc[nf]=__builtin_amdgcn_mfma_f32_16x16x32_bf16(av,bv,acc[nf],0,0,0);
      }
    }
  };
  stage(0,0);
  asm volatile("s_waitcnt vmcnt(0)" ::: "memory");
  __syncthreads();
  int cur=0;
  for(int k0=0;;){
    const int kn=k0+64;
    if(kn<K) stage(cur^1,kn);
    compute(cur);
    asm volatile("s_waitcnt vmcnt(0)" ::: "memory");
    __syncthreads();
    if(kn>=K) break;
    k0=kn; cur^=1;
  }
  if constexpr(EPI==1){
    #pragma unroll
    for(int jj=0;jj<4;jj++){
      const int row=(w<<4)+((l>>4)<<2)+jj;
      const int j=(nt<<4)+l15;
      const float iv=acc[0][jj], fv=acc[1][jj], gv=acc[2][jj], ov=acc[3][jj];
      const float cold=cin[(row<<10)+j];
      const float c2=sigm(fv)*cold + sigm(iv)*tanh_(gv);
      const float h2v=sigm(ov)*tanh_(c2);
      cout[(row<<10)+j]=c2;
      const ushort hb=f2bf(h2v);
      AbOut[(row<<11)+1024+j]=hb;
      h2t[(row<<10)+j]=hb;
    }
  } else {
    #pragma unroll
    for(int nf=0;nf<4;nf++){
      const int col=(nt<<6)+(nf<<4)+l15;
      const float bv=btgt[col];
      #pragma unroll
      for(int jj=0;jj<4;jj++){
        const int row=(w<<4)+((l>>4)<<2)+jj;
        qout[(row<<10)+col]=acc[nf][jj]+bv;
      }
    }
  }
}

// ---------------- per-step kernels ----------------

// attention partials: 1024 blocks = b*16 + chunk j (32 rows each)
__global__ __launch_bounds__(256) void k_attn(const ushort* __restrict__ esrc,
    const float* __restrict__ q, const float* __restrict__ sbias,
    float* __restrict__ pm, float* __restrict__ pl, float* __restrict__ pctx)
{
  const int b = blockIdx.x>>4, j = blockIdx.x&15;
  const int tid = threadIdx.x, w = tid>>6, l = tid&63;
  __shared__ float ms[4], ls[4];
  __shared__ float ctxs[4][1024];
  float qr[16];
  {
    const float* qp = q + (b<<10) + (l<<4);
    #pragma unroll
    for(int i=0;i<16;i+=4){ float4 v=*(const float4*)(qp+i); qr[i]=v.x; qr[i+1]=v.y; qr[i+2]=v.z; qr[i+3]=v.w; }
  }
  float m = -3.4e38f, lsum = 0.f;
  float cacc[16];
  #pragma unroll
  for(int i=0;i<16;i++) cacc[i]=0.f;
  const int sbase = (j<<5) + w;
  for(int rr=0; rr<8; rr++){
    const int s = sbase + (rr<<2);
    const ushort* ep = esrc + (((long)((b<<9) + s))<<10) + (l<<4);
    s8v e0 = *(const s8v*)ep, e1 = *(const s8v*)(ep+8);
    float ef[16];
    #pragma unroll
    for(int i=0;i<8;i++){ ef[i]=bf2f((ushort)e0[i]); ef[8+i]=bf2f((ushort)e1[i]); }
    float d = 0.f;
    #pragma unroll
    for(int i=0;i<16;i++) d += ef[i]*qr[i];
    d = wred(d);
    d += sbias[(b<<9)+s];
    const float mn = fmaxf(m, d);
    const float sc = __expf(m - mn);
    const float p = __expf(d - mn);
    lsum = lsum*sc + p;
    #pragma unroll
    for(int i=0;i<16;i++) cacc[i] = cacc[i]*sc + p*ef[i];
    m = mn;
  }
  if(l==0){ ms[w]=m; ls[w]=lsum; }
  #pragma unroll
  for(int i=0;i<16;i++) ctxs[w][(l<<4)+i]=cacc[i];
  __syncthreads();
  const float mb = fmaxf(fmaxf(ms[0],ms[1]),fmaxf(ms[2],ms[3]));
  const float w0=__expf(ms[0]-mb), w1=__expf(ms[1]-mb), w2=__expf(ms[2]-mb), w3=__expf(ms[3]-mb);
  const float lb = ls[0]*w0 + ls[1]*w1 + ls[2]*w2 + ls[3]*w3;
  const int jb = (j<<6) + b;
  float* pc = pctx + ((long)jb<<10);
  for(int d0=tid; d0<1024; d0+=256){
    pc[d0] = ctxs[0][d0]*w0 + ctxs[1][d0]*w1 + ctxs[2][d0]*w2 + ctxs[3][d0]*w3;
  }
  if(tid==0){ pm[jb]=mb; pl[jb]=lb; }
}

// combine 16 attn partials -> ctx bf16 into Abuf cols 0:1024 (32 blocks)
__global__ __launch_bounds__(256) void k_combine(const float* __restrict__ pm,
    const float* __restrict__ pl, const float* __restrict__ pctx, ushort* __restrict__ Ab)
{
  const int idx = blockIdx.x*256 + threadIdx.x;   // 0..8191
  const int b = idx>>7, c0 = (idx&127)<<3;
  float mv[16];
  #pragma unroll
  for(int j=0;j<16;j++) mv[j] = pm[(j<<6)+b];
  float M = mv[0];
  #pragma unroll
  for(int j=1;j<16;j++) M = fmaxf(M, mv[j]);
  float e[16]; float den = 0.f;
  #pragma unroll
  for(int j=0;j<16;j++){ e[j] = __expf(mv[j]-M); den += pl[(j<<6)+b]*e[j]; }
  const float inv = 1.f/den;
  float s0=0,s1=0,s2=0,s3=0,s4=0,s5=0,s6=0,s7=0;
  #pragma unroll
  for(int j=0;j<16;j++){
    const float wj = e[j]*inv;
    const float* p = pctx + (((long)((j<<6)+b))<<10) + c0;
    float4 v0=*(const float4*)p, v1=*(const float4*)(p+4);
    s0+=wj*v0.x; s1+=wj*v0.y; s2+=wj*v0.z; s3+=wj*v0.w;
    s4+=wj*v1.x; s5+=wj*v1.y; s6+=wj*v1.z; s7+=wj*v1.w;
  }
  s8v o;
  o[0]=(short)f2bf(s0); o[1]=(short)f2bf(s1); o[2]=(short)f2bf(s2); o[3]=(short)f2bf(s3);
  o[4]=(short)f2bf(s4); o[5]=(short)f2bf(s5); o[6]=(short)f2bf(s6); o[7]=(short)f2bf(s7);
  *(s8v*)&Ab[(b<<11)+c0] = o;
}

// selected-head LSE + gold logprob per (t,b): grid 640, wave = one (t,b)
__global__ __launch_bounds__(256) void k_loss2(const float* __restrict__ la,
    const float* __restrict__ lcb, const float* __restrict__ ltb,
    const float* __restrict__ ca, const float* __restrict__ cb, const float* __restrict__ ct,
    const int* __restrict__ gold, const int* __restrict__ kindv, float* __restrict__ lossbuf)
{
  const int wv = threadIdx.x>>6, l = threadIdx.x&63;
  const int tb = blockIdx.x*4 + wv;   // 0..2559
  const int t = tb>>6, b = tb&63;
  const int kd = kindv[tb];
  const int gi = gold[tb];
  const float* ptr; const float* cons; int R;
  if(kd==0){ ptr = la + (long)tb*128; cons = ca + (b<<7); R=128; }
  else if(kd==1){ ptr = lcb + (long)b*2560 + t*64; cons = cb + (b<<6); R=64; }
  else { ptr = ltb + (long)b*2560 + t*64; cons = ct + (b<<5); R=32; }
  const int gidx = gi & (R-1);
  const float v  = (l < R) ? (ptr[l] + cons[l]) : -3.4e38f;
  const float v2 = (R==128) ? (ptr[l+64] + cons[l+64]) : -3.4e38f;
  float mx = fmaxf(v, v2);
  #pragma unroll
  for(int off=32; off; off>>=1) mx = fmaxf(mx, __shfl_xor(mx, off, 64));
  float s = ((l<R)?__expf(v-mx):0.f) + ((R==128)?__expf(v2-mx):0.f);
  s = wred(s);
  const float gv = ptr[gidx] + cons[gidx];
  if(l==0) lossbuf[tb] = gv - (mx + __logf(s));
}

__global__ void k_loss_fin(const float* __restrict__ lossbuf, float* __restrict__ out){
  int b = threadIdx.x;
  if(b < 64){
    float s = 0.f;
    for(int t=0;t<40;t++) s += lossbuf[(t<<6)+b];
    out[b] = -s;
  }
}

// ---------------- host ----------------

extern "C" void kernel_launch(void* const* d_in, const int* in_sizes, int n_in,
                              void* d_out, int out_size, void* d_ws, size_t ws_size,
                              hipStream_t stream)
{
  const float *e_src=(const float*)d_in[0], *e_col=(const float*)d_in[1], *e_tab=(const float*)d_in[2];
  const float *h0=(const float*)d_in[3], *c0=(const float*)d_in[4];
  const float *emba=(const float*)d_in[5], *embs=(const float*)d_in[6];
  const float *W_tgt=(const float*)d_in[7], *b_tgt=(const float*)d_in[8];
  const float *W_act=(const float*)d_in[9], *b_act=(const float*)d_in[10];
  const float *W_col=(const float*)d_in[11], *b_col=(const float*)d_in[12];
  const float *W_tab=(const float*)d_in[13], *b_tab=(const float*)d_in[14];
  const float *W_out=(const float*)d_in[15], *b_out=(const float*)d_in[16];
  const float *W_ih=(const float*)d_in[17], *b_ih=(const float*)d_in[18];
  const float *W_hh=(const float*)d_in[19], *b_hh=(const float*)d_in[20];
  const int *smask=(const int*)d_in[21], *cmask=(const int*)d_in[22], *tmask=(const int*)d_in[23];
  const int *amask=(const int*)d_in[24];
  const int *cur=(const int*)d_in[25], *kindp=(const int*)d_in[26], *goldp=(const int*)d_in[27];

  char* wp = (char*)d_ws;
  auto alloc = [&](size_t n)->char*{ char* p = wp; wp += (n + 255) & ~(size_t)255; return p; };
  ushort* esrc_bf = (ushort*)alloc(67108864);
  ushort* WihT    = (ushort*)alloc(16777216);
  ushort* WcatP   = (ushort*)alloc(16777216);
  ushort* WtgtT   = (ushort*)alloc(2097152);
  ushort* BcatT   = (ushort*)alloc(6291456);
  ushort* Woutb   = (ushort*)alloc(2097152);
  float*  U       = (float*) alloc(12582912);   // aliased later by P
  ushort* Ubf     = (ushort*)alloc(6291456);
  ushort* GAt     = (ushort*)alloc(262144);
  ushort* GCt     = (ushort*)alloc(8388608);
  ushort* GTt     = (ushort*)alloc(8388608);    // padded: 64 rows per batch
  ushort* gpre    = (ushort*)alloc(20971520);
  float* biasvec  = (float*)alloc(16384);
  float* sbias    = (float*)alloc(131072);
  float* vv       = (float*)alloc(12288);
  float* dbuf     = (float*)alloc(25088);
  float* ca       = (float*)alloc(32768);
  float* cb       = (float*)alloc(16384);
  float* ctb      = (float*)alloc(8192);
  float* pm       = (float*)alloc(4096);
  float* pl       = (float*)alloc(4096);
  float* pctx     = (float*)alloc(4194304);
  ushort* Ab0     = (ushort*)alloc(262144);
  ushort* Ab1     = (ushort*)alloc(262144);
  float* cbuf0    = (float*)alloc(262144);
  float* cbuf1    = (float*)alloc(262144);
  float* qb       = (float*)alloc(262144);
  ushort* h2a     = (ushort*)alloc(5242880);
  float* la       = (float*)alloc(1310720);
  float* lcb      = (float*)alloc(655360);
  float* ltb      = (float*)alloc(655360);
  float* lossbuf  = (float*)alloc(10240);
  ushort* P       = (ushort*)U;                 // alias: P used after U is consumed
  float* out      = (float*)d_out;

  k_cast<<<4096,256,0,stream>>>(e_src, esrc_bf, 8388608L);
  k_cast<<<512,256,0,stream>>>(W_out, Woutb, 262144L);
  k_tr7<<<5120,256,0,stream>>>(W_ih, W_hh, W_tgt, W_col, W_tab, W_act,
                               WihT, WcatP, WtgtT, BcatT);
  k_init<<<256,256,0,stream>>>(h0, c0, b_ih, b_hh, smask, cbuf0, Ab0, biasvec, sbias);

  { dim3 g(24,8); k_gemm128<false,false><<<g,256,0,stream>>>(Woutb, BcatT, U, nullptr, 3072, 1024); }
  k_cast<<<1024,256,0,stream>>>(U, Ubf, 786432L);
  { dim3 g(16,2); k_gemm<true,true,false><<<g,256,0,stream>>>(emba, Ubf+2048, GAt, nullptr,
        128,1024,1024, 1024,3072,1024, 0,0,0); }
  { dim3 g(16,1,64); k_gemm<true,true,false><<<g,256,0,stream>>>(e_col, Ubf, GCt, nullptr,
        64,1024,1024, 1024,3072,1024, 65536,0,65536); }
  { dim3 g(16,1,64); k_gemm<true,true,false><<<g,256,0,stream>>>(e_tab, Ubf+1024, GTt, nullptr,
        32,1024,1024, 1024,3072,1024, 32768,0,65536); }
  k_bias1<<<12,256,0,stream>>>(b_out, W_act, b_act, W_col, b_col, W_tab, b_tab, vv);
  k_bias2a<<<1568,256,0,stream>>>(vv, emba, e_col, e_tab, dbuf);
  k_bias2b<<<56,256,0,stream>>>(dbuf, amask, cmask, tmask, ca, cb, ctb);

  k_gatherP<<<2048,256,0,stream>>>(emba, e_col, e_tab, embs, kindp, goldp, cur, P);
  { dim3 g(32,20); k_gemm128<true,true><<<g,256,0,stream>>>(P, WihT, gpre, biasvec, 4096, 2048); }
  k_sgemm<0><<<16,256,0,stream>>>(Ab0+1024, 2048, WtgtT, 1024, 1024,
        nullptr, nullptr, nullptr, nullptr, nullptr, b_tgt, qb);

  for(int t=0; t<40; t++){
    ushort* Ain  = (t&1) ? Ab1 : Ab0;
    ushort* Aout = (t&1) ? Ab0 : Ab1;
    float* ci = (t&1) ? cbuf1 : cbuf0;
    float* co = (t&1) ? cbuf0 : cbuf1;
    k_attn<<<1024,256,0,stream>>>(esrc_bf, qb, sbias, pm, pl, pctx);
    k_combine<<<32,256,0,stream>>>(pm, pl, pctx, Ain);
    k_sgemm<1><<<64,256,0,stream>>>(Ain, 2048, WcatP, 2048, 2048,
        gpre + (long)t*262144, ci, co, Aout, h2a + (long)t*65536, nullptr, nullptr);
    k_sgemm<0><<<16,256,0,stream>>>(Aout+1024, 2048, WtgtT, 1024, 1024,
        nullptr, nullptr, nullptr, nullptr, nullptr, b_tgt, qb);
  }

  // loss: logits via MFMA GEMMs, then selected-head LSE
  { dim3 g(1,20); k_gemm128<false,false><<<g,256,0,stream>>>(h2a, GAt, la, nullptr, 128, 1024); }
  { dim3 g(1,1,64); k_gemm<false,false,false><<<g,256,0,stream>>>(h2a, GCt, lcb, nullptr,
        40,64,1024, 65536,1024,64, 1024,65536,2560); }
  { dim3 g(1,1,64); k_gemm<false,false,false><<<g,256,0,stream>>>(h2a, GTt, ltb, nullptr,
        40,64,1024, 65536,1024,64, 1024,65536,2560); }
  k_loss2<<<640,256,0,stream>>>(la, lcb, ltb, ca, cb, ctb, goldp, kindp, lossbuf);
  k_loss_fin<<<1,64,0,stream>>>(lossbuf, out);
}

// Round 7
// 2373.048 us; speedup vs baseline: 1.0083x; 1.0083x over previous
//
#include <hip/hip_runtime.h>
#include <math.h>

typedef short s8v __attribute__((ext_vector_type(8)));
typedef __bf16 bf8 __attribute__((ext_vector_type(8)));
typedef float f4v __attribute__((ext_vector_type(4)));

#define DEV static __device__ __forceinline__

DEV ushort f2bf(float f){
  union { float f; unsigned u; } v; v.f = f;
  unsigned u = v.u;
  return (ushort)((u + 0x7fffu + ((u>>16)&1u)) >> 16);
}
DEV float bf2f(ushort u){
  union { unsigned u; float f; } v; v.u = ((unsigned)u)<<16; return v.f;
}
DEV float sigm(float x){ return 1.0f/(1.0f + __expf(-x)); }
DEV float tanh_(float x){ float e=__expf(2.f*x); return 1.f - 2.f/(e+1.f); }
DEV float wred(float x){
  #pragma unroll
  for(int off=32; off; off>>=1) x += __shfl_xor(x, off, 64);
  return x;
}
// swizzled LDS index for a [64][64]-ushort tile; uscol 8-aligned at use sites
DEV int swz(int row, int uscol){
  return (row<<6) + ((((uscol>>3) ^ (row&7))<<3) | (uscol&7));
}
DEV void gload16(const void* g, void* l){
  __builtin_amdgcn_global_load_lds((const __attribute__((address_space(1))) void*)g,
                                   (__attribute__((address_space(3))) void*)l, 16, 0, 0);
}
// gate-col permutation: n (= g*1024 + j) -> n' = (j>>4)*64 + g*16 + (j&15)
DEV int gperm(int n){
  return (((n&1023)>>4)<<6) | ((n>>10)<<4) | (n&15);
}

// ---------------- precompute kernels ----------------

__global__ void k_cast(const float* __restrict__ s, ushort* __restrict__ d, long n4){
  long i = (long)blockIdx.x*256 + threadIdx.x;
  const long st = (long)gridDim.x*256;
  for(; i<n4; i+=st){
    float4 v = ((const float4*)s)[i];
    ushort4 o; o.x=f2bf(v.x); o.y=f2bf(v.y); o.z=f2bf(v.z); o.w=f2bf(v.w);
    ((ushort4*)d)[i]=o;
  }
}

// merged transposes: src f32 [R][C] -> dst bf16 [C][ldd], dst[perm(n)][roff+k] = src[k][n]
__global__ __launch_bounds__(256) void k_tr7(const float* __restrict__ wih,
    const float* __restrict__ whh, const float* __restrict__ wtgt,
    const float* __restrict__ wcol, const float* __restrict__ wtab,
    const float* __restrict__ wact, ushort* __restrict__ WihT,
    ushort* __restrict__ WcatT, ushort* __restrict__ WtgtT, ushort* __restrict__ BcatT)
{
  __shared__ ushort T[64][72];
  const int bid = blockIdx.x;
  const float* src; ushort* dst; int C, ldd, roff, cx, ry; bool pm;
  if(bid < 2048){ src=wih; C=4096; dst=WihT; ldd=2048; roff=0; cx=bid&63; ry=bid>>6; pm=true; }
  else if(bid < 3072){ int j=bid-2048; src=wih+2048L*4096; C=4096; dst=WcatT; ldd=2048; roff=0; cx=j&63; ry=j>>6; pm=true; }
  else if(bid < 4096){ int j=bid-3072; src=whh; C=4096; dst=WcatT; ldd=2048; roff=1024; cx=j&63; ry=j>>6; pm=true; }
  else if(bid < 4352){ int j=bid-4096; src=wtgt; C=1024; dst=WtgtT; ldd=1024; roff=0; cx=j&15; ry=j>>4; pm=false; }
  else if(bid < 4608){ int j=bid-4352; src=wcol; C=1024; dst=BcatT; ldd=1024; roff=0; cx=j&15; ry=j>>4; pm=false; }
  else if(bid < 4864){ int j=bid-4608; src=wtab; C=1024; dst=BcatT+1048576; ldd=1024; roff=0; cx=j&15; ry=j>>4; pm=false; }
  else { int j=bid-4864; src=wact; C=1024; dst=BcatT+2097152; ldd=1024; roff=0; cx=j&15; ry=j>>4; pm=false; }
  const int c0 = cx<<6, r0 = ry<<6;
  const int tid = threadIdx.x;
  {
    const int rr = tid>>2, cc = (tid&3)<<4;
    const float* s = src + (long)(r0+rr)*C + c0 + cc;
    float4 v0=*(const float4*)(s), v1=*(const float4*)(s+4), v2=*(const float4*)(s+8), v3=*(const float4*)(s+12);
    ushort* t = &T[rr][cc];
    t[0]=f2bf(v0.x); t[1]=f2bf(v0.y); t[2]=f2bf(v0.z); t[3]=f2bf(v0.w);
    t[4]=f2bf(v1.x); t[5]=f2bf(v1.y); t[6]=f2bf(v1.z); t[7]=f2bf(v1.w);
    t[8]=f2bf(v2.x); t[9]=f2bf(v2.y); t[10]=f2bf(v2.z); t[11]=f2bf(v2.w);
    t[12]=f2bf(v3.x); t[13]=f2bf(v3.y); t[14]=f2bf(v3.z); t[15]=f2bf(v3.w);
  }
  __syncthreads();
  {
    const int rr = tid>>2, cc = (tid&3)<<4;
    s8v o0, o1;
    #pragma unroll
    for(int i=0;i<8;i++){ o0[i]=(short)T[cc+i][rr]; o1[i]=(short)T[cc+8+i][rr]; }
    const int n = c0 + rr;
    const int nr = pm ? gperm(n) : n;
    ushort* dp = dst + (long)nr*ldd + roff + r0 + cc;
    *(s8v*)dp = o0; *(s8v*)(dp+8) = o1;
  }
}

// P[2560][2048] bf16: cols 0:1024 = prev_emb(t), cols 1024:2048 = node_emb(t)
__global__ void k_gatherP(const float* __restrict__ emba, const float* __restrict__ ecol,
                          const float* __restrict__ etab, const float* __restrict__ symb,
                          const int* __restrict__ kindv, const int* __restrict__ gold,
                          const int* __restrict__ cur, ushort* __restrict__ P){
  long i = (long)blockIdx.x*256 + threadIdx.x;
  const long st = (long)gridDim.x*256;
  const long n4 = 2560L*2048/4;
  for(; i<n4; i+=st){
    long pos = i*4; int row = (int)(pos>>11); int col = (int)(pos&2047);
    int t = row>>6, b = row&63;
    ushort4 o;
    if(col < 1024){
      if(t==0){ o.x=o.y=o.z=o.w=0; *(ushort4*)&P[pos]=o; continue; }
      int k = kindv[(t-1)*64+b];
      int gi = gold[(t-1)*64+b];
      const float* s;
      if(k==0) s = emba + ((long)(gi & 127))*1024 + col;
      else if(k==1) s = ecol + (((long)b<<6) + (gi & 63))*1024 + col;
      else s = etab + (((long)b<<5) + (gi & 31))*1024 + col;
      float4 v = *(const float4*)s;
      o.x=f2bf(v.x); o.y=f2bf(v.y); o.z=f2bf(v.z); o.w=f2bf(v.w);
    } else {
      const float* s = symb + ((long)cur[t*64+b])*1024 + (col-1024);
      float4 v = *(const float4*)s;
      o.x=f2bf(v.x); o.y=f2bf(v.y); o.z=f2bf(v.z); o.w=f2bf(v.w);
    }
    *(ushort4*)&P[pos] = o;
  }
}

__global__ void k_init(const float* __restrict__ h0, const float* __restrict__ c0,
                       const float* __restrict__ bih, const float* __restrict__ bhh,
                       const int* __restrict__ smask,
                       float* __restrict__ cbuf, ushort* __restrict__ Ab0,
                       float* __restrict__ biasvec, float* __restrict__ sbias){
  int i = blockIdx.x*256 + threadIdx.x;
  if(i < 65536){
    cbuf[i]=c0[i];
    int row=i>>10, col=i&1023;
    Ab0[(row<<11)+1024+col]=f2bf(h0[i]);
  }
  if(i < 32768) sbias[i] = (smask[i]==1) ? -1.0e9f : 0.f;
  if(i < 4096){
    int nt=i>>6, g=(i>>4)&3, j16=i&15;
    int n = (g<<10) | (nt<<4) | j16;
    biasvec[i] = bih[n] + bhh[n];
  }
}

__global__ void k_bias1(const float* __restrict__ bout,
                        const float* __restrict__ Wa, const float* __restrict__ ba,
                        const float* __restrict__ Wc, const float* __restrict__ bc,
                        const float* __restrict__ Wt, const float* __restrict__ bt,
                        float* __restrict__ vv){
  int j = blockIdx.x*256 + threadIdx.x;
  if(j >= 3072) return;
  int which = j>>10, col = j&1023;
  const float* W = (which==0)?Wa:(which==1)?Wc:Wt;
  const float* bb = (which==0)?ba:(which==1)?bc:bt;
  float s = bb[col];
  for(int i=0;i<1024;i++) s += bout[i]*W[((long)i<<10)+col];
  vv[j] = s;
}

__global__ void k_bias2a(const float* __restrict__ vv, const float* __restrict__ emb,
                         const float* __restrict__ ecol, const float* __restrict__ etab,
                         float* __restrict__ dbuf){
  int wid = blockIdx.x*4 + (threadIdx.x>>6);
  int l = threadIdx.x & 63;
  if(wid >= 6272) return;
  const float* src; const float* v;
  if(wid < 128){ src = emb + ((long)wid<<10); v = vv; }
  else if(wid < 4224){ src = ecol + ((long)(wid-128)<<10); v = vv+1024; }
  else { src = etab + ((long)(wid-4224)<<10); v = vv+2048; }
  const float* sp = src + l*16; const float* vp = v + l*16;
  float s = 0.f;
  #pragma unroll
  for(int i=0;i<16;i+=4){
    float4 a = *(const float4*)(sp+i); float4 bvv = *(const float4*)(vp+i);
    s += a.x*bvv.x + a.y*bvv.y + a.z*bvv.z + a.w*bvv.w;
  }
  s = wred(s);
  if(l==0) dbuf[wid] = s;
}

__global__ void k_bias2b(const float* __restrict__ dbuf,
                         const int* __restrict__ amask, const int* __restrict__ cmask,
                         const int* __restrict__ tmask,
                         float* __restrict__ ca, float* __restrict__ cb, float* __restrict__ ct){
  int i = blockIdx.x*256 + threadIdx.x;
  if(i < 8192){ ca[i] = dbuf[i&127] + ((amask[i]==1)?-1.0e9f:0.f); }
  else if(i < 12288){ int j=i-8192; cb[j] = dbuf[128+j] + ((cmask[j]==1)?-1.0e9f:0.f); }
  else if(i < 14336){ int j=i-12288; ct[j] = dbuf[4224+j] + ((tmask[j]==1)?-1.0e9f:0.f); }
}

// ---------------- 128x128 m97-style GEMM (global_load_lds, dbuf, swizzled) ----
// C[M,N] = A[M,K] @ B^T ; A [M][K] bf16, B [N][K] bf16. M%128==0, N%128==0, K%64==0.
template<bool OBF16, bool HASB>
__global__ __launch_bounds__(256,2) void k_gemm128(const ushort* __restrict__ Ap,
    const ushort* __restrict__ Bp, void* __restrict__ Cp, const float* __restrict__ bias,
    int N, int K)
{
  __shared__ __align__(16) ushort As[2][8192];
  __shared__ __align__(16) ushort Bs[2][8192];
  const int tid=threadIdx.x, w=tid>>6, l=tid&63;
  const int wr=w>>1, wc=w&1;
  const int m0=blockIdx.y<<7, n0=blockIdx.x<<7;
  const int lr8 = l>>3, lc = l&7;
  f4v acc[4][4];
  #pragma unroll
  for(int m=0;m<4;m++)
    #pragma unroll
    for(int n=0;n<4;n++) acc[m][n]=(f4v){0.f,0.f,0.f,0.f};

  auto stage=[&](int buf, int k0){
    #pragma unroll
    for(int i=0;i<4;i++){
      const int rb = i*32 + w*8;
      const int row = rb + lr8;
      const int cp = (lc ^ (row&7))<<3;
      gload16(Ap + (long)(m0+row)*K + k0 + cp, &As[buf][rb<<6]);
      gload16(Bp + (long)(n0+row)*K + k0 + cp, &Bs[buf][rb<<6]);
    }
  };
  auto compute=[&](int buf){
    #pragma unroll
    for(int ks=0; ks<2; ks++){
      bf8 av[4], bv[4];
      #pragma unroll
      for(int m=0;m<4;m++){
        const int ar = wr*64 + (m<<4) + (l&15);
        const int ch = (ks<<2) + (l>>4);
        av[m] = *(const bf8*)&As[buf][(ar<<6) + ((ch ^ (ar&7))<<3)];
      }
      #pragma unroll
      for(int n=0;n<4;n++){
        const int br = wc*64 + (n<<4) + (l&15);
        const int ch = (ks<<2) + (l>>4);
        bv[n] = *(const bf8*)&Bs[buf][(br<<6) + ((ch ^ (br&7))<<3)];
      }
      #pragma unroll
      for(int m=0;m<4;m++)
        #pragma unroll
        for(int n=0;n<4;n++)
          acc[m][n] = __builtin_amdgcn_mfma_f32_16x16x32_bf16(av[m], bv[n], acc[m][n], 0,0,0);
    }
  };

  stage(0, 0);
  asm volatile("s_waitcnt vmcnt(0)" ::: "memory");
  __syncthreads();
  int cur=0;
  for(int k0=0;;){
    const int kn = k0+64;
    if(kn<K) stage(cur^1, kn);
    compute(cur);
    asm volatile("s_waitcnt vmcnt(0)" ::: "memory");
    __syncthreads();
    if(kn>=K) break;
    k0=kn; cur^=1;
  }
  #pragma unroll
  for(int m=0;m<4;m++){
    #pragma unroll
    for(int n=0;n<4;n++){
      const int col = n0 + wc*64 + (n<<4) + (l&15);
      float bv_ = 0.f;
      if constexpr(HASB) bv_ = bias[col];
      #pragma unroll
      for(int j=0;j<4;j++){
        const int row = m0 + wr*64 + (m<<4) + ((l>>4)<<2) + j;
        float v = acc[m][n][j] + bv_;
        if constexpr(OBF16) ((ushort*)Cp)[(long)row*N + col] = f2bf(v);
        else ((float*)Cp)[(long)row*N + col] = v;
      }
    }
  }
}

// ---------------- small-tile GEMM template (2-deep reg prefetch) ----------------
// C[M,N] = A[M,K] @ B ; B[k][n] = Bp[sBz*z + n*ldb + k]. K%128==0.
template<bool AF32, bool OBF16, bool HASB>
__global__ __launch_bounds__(256) void k_gemm(const void* __restrict__ Ap,
    const ushort* __restrict__ Bp, void* __restrict__ Cp, const float* __restrict__ bias,
    int M, int N, int K, int lda, int ldb, int ldc, long sAz, long sBz, long sCz)
{
  __shared__ __align__(16) ushort As[4096];
  __shared__ __align__(16) ushort Bs[4096];
  const int tid=threadIdx.x, w=tid>>6, l=tid&63, q4=l>>4;
  const int r=tid>>2, cc=(tid&3)<<4;
  const int m0=blockIdx.y<<6, n0=blockIdx.x<<6;
  const int z=blockIdx.z;
  f4v acc[4];
  #pragma unroll
  for(int i=0;i<4;i++) acc[i]=(f4v){0.f,0.f,0.f,0.f};

  struct PF { float4 f0,f1,f2,f3; s8v u0,u1,b0,b1; };
  PF pA, pB;

  auto loadAB=[&](int k0, PF& p){
    const int gm = m0 + r;
    if constexpr(AF32){
      if(gm < M){
        const float* a = (const float*)Ap + sAz*z + (long)gm*lda + k0 + cc;
        p.f0=*(const float4*)(a); p.f1=*(const float4*)(a+4); p.f2=*(const float4*)(a+8); p.f3=*(const float4*)(a+12);
      } else { p.f0=p.f1=p.f2=p.f3=make_float4(0.f,0.f,0.f,0.f); }
    } else {
      if(gm < M){
        const ushort* a = (const ushort*)Ap + sAz*z + (long)gm*lda + k0 + cc;
        p.u0=*(const s8v*)a; p.u1=*(const s8v*)(a+8);
      } else { p.u0=p.u1=(s8v){0,0,0,0,0,0,0,0}; }
    }
    const ushort* b = Bp + sBz*z + (long)(n0+r)*ldb + k0 + cc;
    p.b0=*(const s8v*)b; p.b1=*(const s8v*)(b+8);
  };
  auto stage=[&](const PF& p){
    s8v a0, a1;
    if constexpr(AF32){
      a0[0]=(short)f2bf(p.f0.x); a0[1]=(short)f2bf(p.f0.y); a0[2]=(short)f2bf(p.f0.z); a0[3]=(short)f2bf(p.f0.w);
      a0[4]=(short)f2bf(p.f1.x); a0[5]=(short)f2bf(p.f1.y); a0[6]=(short)f2bf(p.f1.z); a0[7]=(short)f2bf(p.f1.w);
      a1[0]=(short)f2bf(p.f2.x); a1[1]=(short)f2bf(p.f2.y); a1[2]=(short)f2bf(p.f2.z); a1[3]=(short)f2bf(p.f2.w);
      a1[4]=(short)f2bf(p.f3.x); a1[5]=(short)f2bf(p.f3.y); a1[6]=(short)f2bf(p.f3.z); a1[7]=(short)f2bf(p.f3.w);
    } else { a0=p.u0; a1=p.u1; }
    *(s8v*)&As[swz(r,cc)] = a0; *(s8v*)&As[swz(r,cc+8)] = a1;
    *(s8v*)&Bs[swz(r,cc)] = p.b0; *(s8v*)&Bs[swz(r,cc+8)] = p.b1;
  };
  auto compute=[&](){
    #pragma unroll
    for(int ks=0; ks<64; ks+=32){
      bf8 av = *(const bf8*)&As[swz((w<<4)+(l&15), ks+(q4<<3))];
      #pragma unroll
      for(int nf=0; nf<4; nf++){
        bf8 bv = *(const bf8*)&Bs[swz((nf<<4)+(l&15), ks+(q4<<3))];
        acc[nf] = __builtin_amdgcn_mfma_f32_16x16x32_bf16(av, bv, acc[nf], 0, 0, 0);
      }
    }
  };

  loadAB(0, pA); loadAB(64, pB);
  for(int k0=0; k0<K; k0+=128){
    stage(pA); __syncthreads();
    if(k0+128 < K) loadAB(k0+128, pA);
    compute(); __syncthreads();
    stage(pB); __syncthreads();
    if(k0+192 < K) loadAB(k0+192, pB);
    compute(); __syncthreads();
  }
  #pragma unroll
  for(int nf=0; nf<4; nf++){
    const int col = n0 + (nf<<4) + (l&15);
    float bv = 0.f;
    if constexpr(HASB) bv = bias[col];
    #pragma unroll
    for(int j=0;j<4;j++){
      const int row = m0 + (w<<4) + ((l>>4)<<2) + j;
      if(row < M){
        float v = acc[nf][j] + bv;
        if constexpr(OBF16) ((ushort*)Cp)[sCz*z + (long)row*ldc + col] = f2bf(v);
        else ((float*)Cp)[sCz*z + (long)row*ldc + col] = v;
      }
    }
  }
}

// ---------------- per-step small GEMM: 3-buffer counted-vmcnt pipeline ---------
// M=64 fixed. A bf16 [64][lda]; B bf16 [N][ldb], block nt handles cols nt*64..+63.
// EPI==0: q writeout f32 + btgt bias. EPI==1: LSTM cell epilogue (permuted gates).
template<int EPI>
__global__ __launch_bounds__(256) void k_sgemm(
    const ushort* __restrict__ Ap, int lda,
    const ushort* __restrict__ Bp, int ldb, int K,
    const ushort* __restrict__ gpre_t, const float* __restrict__ cin,
    float* __restrict__ cout, ushort* __restrict__ AbOut, ushort* __restrict__ h2t,
    const float* __restrict__ btgt, float* __restrict__ qout)
{
  __shared__ __align__(16) ushort As[3][4096];
  __shared__ __align__(16) ushort Bs[3][4096];
  const int tid=threadIdx.x, w=tid>>6, l=tid&63, l15=l&15;
  const int lr8=l>>3, lc=l&7;
  const int nt=blockIdx.x;
  f4v acc[4];
  if constexpr(EPI==1){
    #pragma unroll
    for(int nf=0;nf<4;nf++){
      #pragma unroll
      for(int jj=0;jj<4;jj++){
        const int row=(w<<4)+((l>>4)<<2)+jj;
        acc[nf][jj]=bf2f(gpre_t[((long)row<<12)+(nt<<6)+(nf<<4)+l15]);
      }
    }
  } else {
    #pragma unroll
    for(int i=0;i<4;i++) acc[i]=(f4v){0.f,0.f,0.f,0.f};
  }
  auto stage=[&](int buf,int k0){
    #pragma unroll
    for(int i=0;i<2;i++){
      const int rb=i*32+w*8;
      const int row=rb+lr8;
      const int cp=(lc^(row&7))<<3;
      gload16(Ap + (long)row*lda + k0 + cp, &As[buf][rb<<6]);
      gload16(Bp + (long)((nt<<6)+row)*ldb + k0 + cp, &Bs[buf][rb<<6]);
    }
  };
  auto compute=[&](int buf){
    #pragma unroll
    for(int ks=0;ks<2;ks++){
      const int ch=(ks<<2)+(l>>4);
      const int ar=(w<<4)+l15;
      bf8 av = *(const bf8*)&As[buf][(ar<<6)+((ch^(ar&7))<<3)];
      #pragma unroll
      for(int nf=0;nf<4;nf++){
        const int br=(nf<<4)+l15;
        bf8 bv = *(const bf8*)&Bs[buf][(br<<6)+((ch^(br&7))<<3)];
        acc[nf]=__builtin_amdgcn_mfma_f32_16x16x32_bf16(av,bv,acc[nf],0,0,0);
      }
    }
  };
  // prologue: 2 tiles in flight (8 loads/thread)
  stage(0,0); stage(1,64);
  int cur=0;
  for(int k0=0; k0<K; k0+=64){
    const int kpre = k0 + 128;
    if(kpre < K){
      // tile cur landed (its 4 loads are the oldest); 4 newest stay in flight
      asm volatile("s_waitcnt vmcnt(4)" ::: "memory");
      __syncthreads();
      int nxt = cur + 2; if(nxt >= 3) nxt -= 3;
      stage(nxt, kpre);
    } else {
      asm volatile("s_waitcnt vmcnt(0)" ::: "memory");
      __syncthreads();
    }
    compute(cur);
    cur++; if(cur==3) cur=0;
  }
  if constexpr(EPI==1){
    #pragma unroll
    for(int jj=0;jj<4;jj++){
      const int row=(w<<4)+((l>>4)<<2)+jj;
      const int j=(nt<<4)+l15;
      const float iv=acc[0][jj], fv=acc[1][jj], gv=acc[2][jj], ov=acc[3][jj];
      const float cold=cin[(row<<10)+j];
      const float c2=sigm(fv)*cold + sigm(iv)*tanh_(gv);
      const float h2v=sigm(ov)*tanh_(c2);
      cout[(row<<10)+j]=c2;
      const ushort hb=f2bf(h2v);
      AbOut[(row<<11)+1024+j]=hb;
      h2t[(row<<10)+j]=hb;
    }
  } else {
    #pragma unroll
    for(int nf=0;nf<4;nf++){
      const int col=(nt<<6)+(nf<<4)+l15;
      const float bv=btgt[col];
      #pragma unroll
      for(int jj=0;jj<4;jj++){
        const int row=(w<<4)+((l>>4)<<2)+jj;
        qout[(row<<10)+col]=acc[nf][jj]+bv;
      }
    }
  }
}

// ---------------- per-step kernels ----------------

// attention partials: 1024 blocks = b*16 + chunk j (32 rows each)
__global__ __launch_bounds__(256) void k_attn(const ushort* __restrict__ esrc,
    const float* __restrict__ q, const float* __restrict__ sbias,
    float* __restrict__ pm, float* __restrict__ pl, float* __restrict__ pctx)
{
  const int b = blockIdx.x>>4, j = blockIdx.x&15;
  const int tid = threadIdx.x, w = tid>>6, l = tid&63;
  __shared__ float ms[4], ls[4];
  __shared__ float ctxs[4][1024];
  float qr[16];
  {
    const float* qp = q + (b<<10) + (l<<4);
    #pragma unroll
    for(int i=0;i<16;i+=4){ float4 v=*(const float4*)(qp+i); qr[i]=v.x; qr[i+1]=v.y; qr[i+2]=v.z; qr[i+3]=v.w; }
  }
  float m = -3.4e38f, lsum = 0.f;
  float cacc[16];
  #pragma unroll
  for(int i=0;i<16;i++) cacc[i]=0.f;
  const int sbase = (j<<5) + w;
  for(int rr=0; rr<8; rr++){
    const int s = sbase + (rr<<2);
    const ushort* ep = esrc + (((long)((b<<9) + s))<<10) + (l<<4);
    s8v e0 = *(const s8v*)ep, e1 = *(const s8v*)(ep+8);
    float ef[16];
    #pragma unroll
    for(int i=0;i<8;i++){ ef[i]=bf2f((ushort)e0[i]); ef[8+i]=bf2f((ushort)e1[i]); }
    float d = 0.f;
    #pragma unroll
    for(int i=0;i<16;i++) d += ef[i]*qr[i];
    d = wred(d);
    d += sbias[(b<<9)+s];
    const float mn = fmaxf(m, d);
    const float sc = __expf(m - mn);
    const float p = __expf(d - mn);
    lsum = lsum*sc + p;
    #pragma unroll
    for(int i=0;i<16;i++) cacc[i] = cacc[i]*sc + p*ef[i];
    m = mn;
  }
  if(l==0){ ms[w]=m; ls[w]=lsum; }
  #pragma unroll
  for(int i=0;i<16;i++) ctxs[w][(l<<4)+i]=cacc[i];
  __syncthreads();
  const float mb = fmaxf(fmaxf(ms[0],ms[1]),fmaxf(ms[2],ms[3]));
  const float w0=__expf(ms[0]-mb), w1=__expf(ms[1]-mb), w2=__expf(ms[2]-mb), w3=__expf(ms[3]-mb);
  const float lb = ls[0]*w0 + ls[1]*w1 + ls[2]*w2 + ls[3]*w3;
  const int jb = (j<<6) + b;
  float* pc = pctx + ((long)jb<<10);
  for(int d0=tid; d0<1024; d0+=256){
    pc[d0] = ctxs[0][d0]*w0 + ctxs[1][d0]*w1 + ctxs[2][d0]*w2 + ctxs[3][d0]*w3;
  }
  if(tid==0){ pm[jb]=mb; pl[jb]=lb; }
}

// combine 16 attn partials -> ctx bf16 into Abuf cols 0:1024 (32 blocks)
__global__ __launch_bounds__(256) void k_combine(const float* __restrict__ pm,
    const float* __restrict__ pl, const float* __restrict__ pctx, ushort* __restrict__ Ab)
{
  const int idx = blockIdx.x*256 + threadIdx.x;   // 0..8191
  const int b = idx>>7, c0 = (idx&127)<<3;
  float mv[16];
  #pragma unroll
  for(int j=0;j<16;j++) mv[j] = pm[(j<<6)+b];
  float M = mv[0];
  #pragma unroll
  for(int j=1;j<16;j++) M = fmaxf(M, mv[j]);
  float e[16]; float den = 0.f;
  #pragma unroll
  for(int j=0;j<16;j++){ e[j] = __expf(mv[j]-M); den += pl[(j<<6)+b]*e[j]; }
  const float inv = 1.f/den;
  float s0=0,s1=0,s2=0,s3=0,s4=0,s5=0,s6=0,s7=0;
  #pragma unroll
  for(int j=0;j<16;j++){
    const float wj = e[j]*inv;
    const float* p = pctx + (((long)((j<<6)+b))<<10) + c0;
    float4 v0=*(const float4*)p, v1=*(const float4*)(p+4);
    s0+=wj*v0.x; s1+=wj*v0.y; s2+=wj*v0.z; s3+=wj*v0.w;
    s4+=wj*v1.x; s5+=wj*v1.y; s6+=wj*v1.z; s7+=wj*v1.w;
  }
  s8v o;
  o[0]=(short)f2bf(s0); o[1]=(short)f2bf(s1); o[2]=(short)f2bf(s2); o[3]=(short)f2bf(s3);
  o[4]=(short)f2bf(s4); o[5]=(short)f2bf(s5); o[6]=(short)f2bf(s6); o[7]=(short)f2bf(s7);
  *(s8v*)&Ab[(b<<11)+c0] = o;
}

// selected-head LSE + gold logprob per (t,b): grid 640, wave = one (t,b)
__global__ __launch_bounds__(256) void k_loss2(const float* __restrict__ la,
    const float* __restrict__ lcb, const float* __restrict__ ltb,
    const float* __restrict__ ca, const float* __restrict__ cb, const float* __restrict__ ct,
    const int* __restrict__ gold, const int* __restrict__ kindv, float* __restrict__ lossbuf)
{
  const int wv = threadIdx.x>>6, l = threadIdx.x&63;
  const int tb = blockIdx.x*4 + wv;   // 0..2559
  const int t = tb>>6, b = tb&63;
  const int kd = kindv[tb];
  const int gi = gold[tb];
  const float* ptr; const float* cons; int R;
  if(kd==0){ ptr = la + (long)tb*128; cons = ca + (b<<7); R=128; }
  else if(kd==1){ ptr = lcb + (long)b*2560 + t*64; cons = cb + (b<<6); R=64; }
  else { ptr = ltb + (long)b*2560 + t*64; cons = ct + (b<<5); R=32; }
  const int gidx = gi & (R-1);
  const float v  = (l < R) ? (ptr[l] + cons[l]) : -3.4e38f;
  const float v2 = (R==128) ? (ptr[l+64] + cons[l+64]) : -3.4e38f;
  float mx = fmaxf(v, v2);
  #pragma unroll
  for(int off=32; off; off>>=1) mx = fmaxf(mx, __shfl_xor(mx, off, 64));
  float s = ((l<R)?__expf(v-mx):0.f) + ((R==128)?__expf(v2-mx):0.f);
  s = wred(s);
  const float gv = ptr[gidx] + cons[gidx];
  if(l==0) lossbuf[tb] = gv - (mx + __logf(s));
}

__global__ void k_loss_fin(const float* __restrict__ lossbuf, float* __restrict__ out){
  int b = threadIdx.x;
  if(b < 64){
    float s = 0.f;
    for(int t=0;t<40;t++) s += lossbuf[(t<<6)+b];
    out[b] = -s;
  }
}

// ---------------- host ----------------

extern "C" void kernel_launch(void* const* d_in, const int* in_sizes, int n_in,
                              void* d_out, int out_size, void* d_ws, size_t ws_size,
                              hipStream_t stream)
{
  const float *e_src=(const float*)d_in[0], *e_col=(const float*)d_in[1], *e_tab=(const float*)d_in[2];
  const float *h0=(const float*)d_in[3], *c0=(const float*)d_in[4];
  const float *emba=(const float*)d_in[5], *embs=(const float*)d_in[6];
  const float *W_tgt=(const float*)d_in[7], *b_tgt=(const float*)d_in[8];
  const float *W_act=(const float*)d_in[9], *b_act=(const float*)d_in[10];
  const float *W_col=(const float*)d_in[11], *b_col=(const float*)d_in[12];
  const float *W_tab=(const float*)d_in[13], *b_tab=(const float*)d_in[14];
  const float *W_out=(const float*)d_in[15], *b_out=(const float*)d_in[16];
  const float *W_ih=(const float*)d_in[17], *b_ih=(const float*)d_in[18];
  const float *W_hh=(const float*)d_in[19], *b_hh=(const float*)d_in[20];
  const int *smask=(const int*)d_in[21], *cmask=(const int*)d_in[22], *tmask=(const int*)d_in[23];
  const int *amask=(const int*)d_in[24];
  const int *cur=(const int*)d_in[25], *kindp=(const int*)d_in[26], *goldp=(const int*)d_in[27];

  char* wp = (char*)d_ws;
  auto alloc = [&](size_t n)->char*{ char* p = wp; wp += (n + 255) & ~(size_t)255; return p; };
  ushort* esrc_bf = (ushort*)alloc(67108864);
  ushort* WihT    = (ushort*)alloc(16777216);
  ushort* WcatP   = (ushort*)alloc(16777216);
  ushort* WtgtT   = (ushort*)alloc(2097152);
  ushort* BcatT   = (ushort*)alloc(6291456);
  ushort* Woutb   = (ushort*)alloc(2097152);
  float*  U       = (float*) alloc(12582912);   // aliased later by P
  ushort* Ubf     = (ushort*)alloc(6291456);
  ushort* GAt     = (ushort*)alloc(262144);
  ushort* GCt     = (ushort*)alloc(8388608);
  ushort* GTt     = (ushort*)alloc(8388608);    // padded: 64 rows per batch
  ushort* gpre    = (ushort*)alloc(20971520);
  float* biasvec  = (float*)alloc(16384);
  float* sbias    = (float*)alloc(131072);
  float* vv       = (float*)alloc(12288);
  float* dbuf     = (float*)alloc(25088);
  float* ca       = (float*)alloc(32768);
  float* cb       = (float*)alloc(16384);
  float* ctb      = (float*)alloc(8192);
  float* pm       = (float*)alloc(4096);
  float* pl       = (float*)alloc(4096);
  float* pctx     = (float*)alloc(4194304);
  ushort* Ab0     = (ushort*)alloc(262144);
  ushort* Ab1     = (ushort*)alloc(262144);
  float* cbuf0    = (float*)alloc(262144);
  float* cbuf1    = (float*)alloc(262144);
  float* qb       = (float*)alloc(262144);
  ushort* h2a     = (ushort*)alloc(5242880);
  float* la       = (float*)alloc(1310720);
  float* lcb      = (float*)alloc(655360);
  float* ltb      = (float*)alloc(655360);
  float* lossbuf  = (float*)alloc(10240);
  ushort* P       = (ushort*)U;                 // alias: P used after U is consumed
  float* out      = (float*)d_out;

  k_cast<<<4096,256,0,stream>>>(e_src, esrc_bf, 8388608L);
  k_cast<<<512,256,0,stream>>>(W_out, Woutb, 262144L);
  k_tr7<<<5120,256,0,stream>>>(W_ih, W_hh, W_tgt, W_col, W_tab, W_act,
                               WihT, WcatP, WtgtT, BcatT);
  k_init<<<256,256,0,stream>>>(h0, c0, b_ih, b_hh, smask, cbuf0, Ab0, biasvec, sbias);

  { dim3 g(24,8); k_gemm128<false,false><<<g,256,0,stream>>>(Woutb, BcatT, U, nullptr, 3072, 1024); }
  k_cast<<<1024,256,0,stream>>>(U, Ubf, 786432L);
  { dim3 g(16,2); k_gemm<true,true,false><<<g,256,0,stream>>>(emba, Ubf+2048, GAt, nullptr,
        128,1024,1024, 1024,3072,1024, 0,0,0); }
  { dim3 g(16,1,64); k_gemm<true,true,false><<<g,256,0,stream>>>(e_col, Ubf, GCt, nullptr,
        64,1024,1024, 1024,3072,1024, 65536,0,65536); }
  { dim3 g(16,1,64); k_gemm<true,true,false><<<g,256,0,stream>>>(e_tab, Ubf+1024, GTt, nullptr,
        32,1024,1024, 1024,3072,1024, 32768,0,65536); }
  k_bias1<<<12,256,0,stream>>>(b_out, W_act, b_act, W_col, b_col, W_tab, b_tab, vv);
  k_bias2a<<<1568,256,0,stream>>>(vv, emba, e_col, e_tab, dbuf);
  k_bias2b<<<56,256,0,stream>>>(dbuf, amask, cmask, tmask, ca, cb, ctb);

  k_gatherP<<<2048,256,0,stream>>>(emba, e_col, e_tab, embs, kindp, goldp, cur, P);
  { dim3 g(32,20); k_gemm128<true,true><<<g,256,0,stream>>>(P, WihT, gpre, biasvec, 4096, 2048); }
  k_sgemm<0><<<16,256,0,stream>>>(Ab0+1024, 2048, WtgtT, 1024, 1024,
        nullptr, nullptr, nullptr, nullptr, nullptr, b_tgt, qb);

  for(int t=0; t<40; t++){
    ushort* Ain  = (t&1) ? Ab1 : Ab0;
    ushort* Aout = (t&1) ? Ab0 : Ab1;
    float* ci = (t&1) ? cbuf1 : cbuf0;
    float* co = (t&1) ? cbuf0 : cbuf1;
    k_attn<<<1024,256,0,stream>>>(esrc_bf, qb, sbias, pm, pl, pctx);
    k_combine<<<32,256,0,stream>>>(pm, pl, pctx, Ain);
    k_sgemm<1><<<64,256,0,stream>>>(Ain, 2048, WcatP, 2048, 2048,
        gpre + (long)t*262144, ci, co, Aout, h2a + (long)t*65536, nullptr, nullptr);
    k_sgemm<0><<<16,256,0,stream>>>(Aout+1024, 2048, WtgtT, 1024, 1024,
        nullptr, nullptr, nullptr, nullptr, nullptr, b_tgt, qb);
  }

  // loss: logits via MFMA GEMMs, then selected-head LSE
  { dim3 g(1,20); k_gemm128<false,false><<<g,256,0,stream>>>(h2a, GAt, la, nullptr, 128, 1024); }
  { dim3 g(1,1,64); k_gemm<false,false,false><<<g,256,0,stream>>>(h2a, GCt, lcb, nullptr,
        40,64,1024, 65536,1024,64, 1024,65536,2560); }
  { dim3 g(1,1,64); k_gemm<false,false,false><<<g,256,0,stream>>>(h2a, GTt, ltb, nullptr,
        40,64,1024, 65536,1024,64, 1024,65536,2560); }
  k_loss2<<<640,256,0,stream>>>(la, lcb, ltb, ca, cb, ctb, goldp, kindp, lossbuf);
  k_loss_fin<<<1,64,0,stream>>>(lossbuf, out);
}

// Round 8
// 2079.993 us; speedup vs baseline: 1.1504x; 1.1409x over previous
//
#include <hip/hip_runtime.h>
#include <math.h>

typedef short s8v __attribute__((ext_vector_type(8)));
typedef __bf16 bf8 __attribute__((ext_vector_type(8)));
typedef float f4v __attribute__((ext_vector_type(4)));

#define DEV static __device__ __forceinline__

DEV ushort f2bf(float f){
  union { float f; unsigned u; } v; v.f = f;
  unsigned u = v.u;
  return (ushort)((u + 0x7fffu + ((u>>16)&1u)) >> 16);
}
DEV float bf2f(ushort u){
  union { unsigned u; float f; } v; v.u = ((unsigned)u)<<16; return v.f;
}
DEV float sigm(float x){ return 1.0f/(1.0f + __expf(-x)); }
DEV float tanh_(float x){ float e=__expf(2.f*x); return 1.f - 2.f/(e+1.f); }
DEV float wred(float x){
  #pragma unroll
  for(int off=32; off; off>>=1) x += __shfl_xor(x, off, 64);
  return x;
}
// swizzled LDS index for a [64][64]-ushort tile; uscol 8-aligned at use sites
DEV int swz(int row, int uscol){
  return (row<<6) + ((((uscol>>3) ^ (row&7))<<3) | (uscol&7));
}
DEV void gload16(const void* g, void* l){
  __builtin_amdgcn_global_load_lds((const __attribute__((address_space(1))) void*)g,
                                   (__attribute__((address_space(3))) void*)l, 16, 0, 0);
}
// gate-col permutation: n (= g*1024 + j) -> n' = (j>>4)*64 + g*16 + (j&15)
DEV int gperm(int n){
  return (((n&1023)>>4)<<6) | ((n>>10)<<4) | (n&15);
}

// ---------------- precompute kernels ----------------

__global__ void k_cast(const float* __restrict__ s, ushort* __restrict__ d, long n4){
  long i = (long)blockIdx.x*256 + threadIdx.x;
  const long st = (long)gridDim.x*256;
  for(; i<n4; i+=st){
    float4 v = ((const float4*)s)[i];
    ushort4 o; o.x=f2bf(v.x); o.y=f2bf(v.y); o.z=f2bf(v.z); o.w=f2bf(v.w);
    ((ushort4*)d)[i]=o;
  }
}

// merged transposes: src f32 [R][C] -> dst bf16 [C][ldd], dst[perm(n)][roff+k] = src[k][n]
__global__ __launch_bounds__(256) void k_tr7(const float* __restrict__ wih,
    const float* __restrict__ whh, const float* __restrict__ wtgt,
    const float* __restrict__ wcol, const float* __restrict__ wtab,
    const float* __restrict__ wact, ushort* __restrict__ WihT,
    ushort* __restrict__ WcatT, ushort* __restrict__ WtgtT, ushort* __restrict__ BcatT)
{
  __shared__ ushort T[64][72];
  const int bid = blockIdx.x;
  const float* src; ushort* dst; int C, ldd, roff, cx, ry; bool pm;
  if(bid < 2048){ src=wih; C=4096; dst=WihT; ldd=2048; roff=0; cx=bid&63; ry=bid>>6; pm=true; }
  else if(bid < 3072){ int j=bid-2048; src=wih+2048L*4096; C=4096; dst=WcatT; ldd=2048; roff=0; cx=j&63; ry=j>>6; pm=true; }
  else if(bid < 4096){ int j=bid-3072; src=whh; C=4096; dst=WcatT; ldd=2048; roff=1024; cx=j&63; ry=j>>6; pm=true; }
  else if(bid < 4352){ int j=bid-4096; src=wtgt; C=1024; dst=WtgtT; ldd=1024; roff=0; cx=j&15; ry=j>>4; pm=false; }
  else if(bid < 4608){ int j=bid-4352; src=wcol; C=1024; dst=BcatT; ldd=1024; roff=0; cx=j&15; ry=j>>4; pm=false; }
  else if(bid < 4864){ int j=bid-4608; src=wtab; C=1024; dst=BcatT+1048576; ldd=1024; roff=0; cx=j&15; ry=j>>4; pm=false; }
  else { int j=bid-4864; src=wact; C=1024; dst=BcatT+2097152; ldd=1024; roff=0; cx=j&15; ry=j>>4; pm=false; }
  const int c0 = cx<<6, r0 = ry<<6;
  const int tid = threadIdx.x;
  {
    const int rr = tid>>2, cc = (tid&3)<<4;
    const float* s = src + (long)(r0+rr)*C + c0 + cc;
    float4 v0=*(const float4*)(s), v1=*(const float4*)(s+4), v2=*(const float4*)(s+8), v3=*(const float4*)(s+12);
    ushort* t = &T[rr][cc];
    t[0]=f2bf(v0.x); t[1]=f2bf(v0.y); t[2]=f2bf(v0.z); t[3]=f2bf(v0.w);
    t[4]=f2bf(v1.x); t[5]=f2bf(v1.y); t[6]=f2bf(v1.z); t[7]=f2bf(v1.w);
    t[8]=f2bf(v2.x); t[9]=f2bf(v2.y); t[10]=f2bf(v2.z); t[11]=f2bf(v2.w);
    t[12]=f2bf(v3.x); t[13]=f2bf(v3.y); t[14]=f2bf(v3.z); t[15]=f2bf(v3.w);
  }
  __syncthreads();
  {
    const int rr = tid>>2, cc = (tid&3)<<4;
    s8v o0, o1;
    #pragma unroll
    for(int i=0;i<8;i++){ o0[i]=(short)T[cc+i][rr]; o1[i]=(short)T[cc+8+i][rr]; }
    const int n = c0 + rr;
    const int nr = pm ? gperm(n) : n;
    ushort* dp = dst + (long)nr*ldd + roff + r0 + cc;
    *(s8v*)dp = o0; *(s8v*)(dp+8) = o1;
  }
}

// P[2560][2048] bf16: cols 0:1024 = prev_emb(t), cols 1024:2048 = node_emb(t)
__global__ void k_gatherP(const float* __restrict__ emba, const float* __restrict__ ecol,
                          const float* __restrict__ etab, const float* __restrict__ symb,
                          const int* __restrict__ kindv, const int* __restrict__ gold,
                          const int* __restrict__ cur, ushort* __restrict__ P){
  long i = (long)blockIdx.x*256 + threadIdx.x;
  const long st = (long)gridDim.x*256;
  const long n4 = 2560L*2048/4;
  for(; i<n4; i+=st){
    long pos = i*4; int row = (int)(pos>>11); int col = (int)(pos&2047);
    int t = row>>6, b = row&63;
    ushort4 o;
    if(col < 1024){
      if(t==0){ o.x=o.y=o.z=o.w=0; *(ushort4*)&P[pos]=o; continue; }
      int k = kindv[(t-1)*64+b];
      int gi = gold[(t-1)*64+b];
      const float* s;
      if(k==0) s = emba + ((long)(gi & 127))*1024 + col;
      else if(k==1) s = ecol + (((long)b<<6) + (gi & 63))*1024 + col;
      else s = etab + (((long)b<<5) + (gi & 31))*1024 + col;
      float4 v = *(const float4*)s;
      o.x=f2bf(v.x); o.y=f2bf(v.y); o.z=f2bf(v.z); o.w=f2bf(v.w);
    } else {
      const float* s = symb + ((long)cur[t*64+b])*1024 + (col-1024);
      float4 v = *(const float4*)s;
      o.x=f2bf(v.x); o.y=f2bf(v.y); o.z=f2bf(v.z); o.w=f2bf(v.w);
    }
    *(ushort4*)&P[pos] = o;
  }
}

__global__ void k_init(const float* __restrict__ h0, const float* __restrict__ c0,
                       const float* __restrict__ bih, const float* __restrict__ bhh,
                       const int* __restrict__ smask,
                       float* __restrict__ cbuf, ushort* __restrict__ Ab0,
                       float* __restrict__ biasvec, float* __restrict__ sbias){
  int i = blockIdx.x*256 + threadIdx.x;
  if(i < 65536){
    cbuf[i]=c0[i];
    int row=i>>10, col=i&1023;
    Ab0[(row<<11)+1024+col]=f2bf(h0[i]);
  }
  if(i < 32768) sbias[i] = (smask[i]==1) ? -1.0e9f : 0.f;
  if(i < 4096){
    int nt=i>>6, g=(i>>4)&3, j16=i&15;
    int n = (g<<10) | (nt<<4) | j16;
    biasvec[i] = bih[n] + bhh[n];
  }
}

// vv[3][1024]: b_out@W_act+b_act | b_out@W_col+b_col | b_out@W_tab+b_tab
// wave-per-column, coalesced bf16 row reads from BcatT (replaces serial k_bias1).
__global__ __launch_bounds__(256) void k_bias1b(const float* __restrict__ bout,
    const ushort* __restrict__ BcatT, const float* __restrict__ ba,
    const float* __restrict__ bc, const float* __restrict__ bt,
    float* __restrict__ vv)
{
  const int wid = blockIdx.x*4 + (threadIdx.x>>6);   // 0..3071
  const int l = threadIdx.x & 63;
  const int which = wid>>10, col = wid&1023;
  const ushort* W = (which==0) ? (BcatT + 2097152)   // W_act^T
                  : (which==1) ? BcatT                // W_col^T
                               : (BcatT + 1048576);   // W_tab^T
  const float bb = ((which==0)?ba:(which==1)?bc:bt)[col];
  const ushort* wp = W + (long)col*1024 + l*16;
  const float* bp = bout + l*16;
  s8v w0 = *(const s8v*)wp, w1 = *(const s8v*)(wp+8);
  float s = 0.f;
  #pragma unroll
  for(int i=0;i<8;i++){
    s += bf2f((ushort)w0[i]) * bp[i];
    s += bf2f((ushort)w1[i]) * bp[8+i];
  }
  s = wred(s);
  if(l==0) vv[wid] = bb + s;
}

__global__ void k_bias2a(const float* __restrict__ vv, const float* __restrict__ emb,
                         const float* __restrict__ ecol, const float* __restrict__ etab,
                         float* __restrict__ dbuf){
  int wid = blockIdx.x*4 + (threadIdx.x>>6);
  int l = threadIdx.x & 63;
  if(wid >= 6272) return;
  const float* src; const float* v;
  if(wid < 128){ src = emb + ((long)wid<<10); v = vv; }
  else if(wid < 4224){ src = ecol + ((long)(wid-128)<<10); v = vv+1024; }
  else { src = etab + ((long)(wid-4224)<<10); v = vv+2048; }
  const float* sp = src + l*16; const float* vp = v + l*16;
  float s = 0.f;
  #pragma unroll
  for(int i=0;i<16;i+=4){
    float4 a = *(const float4*)(sp+i); float4 bvv = *(const float4*)(vp+i);
    s += a.x*bvv.x + a.y*bvv.y + a.z*bvv.z + a.w*bvv.w;
  }
  s = wred(s);
  if(l==0) dbuf[wid] = s;
}

__global__ void k_bias2b(const float* __restrict__ dbuf,
                         const int* __restrict__ amask, const int* __restrict__ cmask,
                         const int* __restrict__ tmask,
                         float* __restrict__ ca, float* __restrict__ cb, float* __restrict__ ct){
  int i = blockIdx.x*256 + threadIdx.x;
  if(i < 8192){ ca[i] = dbuf[i&127] + ((amask[i]==1)?-1.0e9f:0.f); }
  else if(i < 12288){ int j=i-8192; cb[j] = dbuf[128+j] + ((cmask[j]==1)?-1.0e9f:0.f); }
  else if(i < 14336){ int j=i-12288; ct[j] = dbuf[4224+j] + ((tmask[j]==1)?-1.0e9f:0.f); }
}

// ---------------- 128x128 m97-style GEMM (global_load_lds, dbuf, swizzled) ----
// C[M,N] = A[M,K] @ B^T ; A [M][K] bf16, B [N][K] bf16. M%128==0, N%128==0, K%64==0.
template<bool OBF16, bool HASB>
__global__ __launch_bounds__(256,2) void k_gemm128(const ushort* __restrict__ Ap,
    const ushort* __restrict__ Bp, void* __restrict__ Cp, const float* __restrict__ bias,
    int N, int K)
{
  __shared__ __align__(16) ushort As[2][8192];
  __shared__ __align__(16) ushort Bs[2][8192];
  const int tid=threadIdx.x, w=tid>>6, l=tid&63;
  const int wr=w>>1, wc=w&1;
  const int m0=blockIdx.y<<7, n0=blockIdx.x<<7;
  const int lr8 = l>>3, lc = l&7;
  f4v acc[4][4];
  #pragma unroll
  for(int m=0;m<4;m++)
    #pragma unroll
    for(int n=0;n<4;n++) acc[m][n]=(f4v){0.f,0.f,0.f,0.f};

  auto stage=[&](int buf, int k0){
    #pragma unroll
    for(int i=0;i<4;i++){
      const int rb = i*32 + w*8;
      const int row = rb + lr8;
      const int cp = (lc ^ (row&7))<<3;
      gload16(Ap + (long)(m0+row)*K + k0 + cp, &As[buf][rb<<6]);
      gload16(Bp + (long)(n0+row)*K + k0 + cp, &Bs[buf][rb<<6]);
    }
  };
  auto compute=[&](int buf){
    #pragma unroll
    for(int ks=0; ks<2; ks++){
      bf8 av[4], bv[4];
      #pragma unroll
      for(int m=0;m<4;m++){
        const int ar = wr*64 + (m<<4) + (l&15);
        const int ch = (ks<<2) + (l>>4);
        av[m] = *(const bf8*)&As[buf][(ar<<6) + ((ch ^ (ar&7))<<3)];
      }
      #pragma unroll
      for(int n=0;n<4;n++){
        const int br = wc*64 + (n<<4) + (l&15);
        const int ch = (ks<<2) + (l>>4);
        bv[n] = *(const bf8*)&Bs[buf][(br<<6) + ((ch ^ (br&7))<<3)];
      }
      #pragma unroll
      for(int m=0;m<4;m++)
        #pragma unroll
        for(int n=0;n<4;n++)
          acc[m][n] = __builtin_amdgcn_mfma_f32_16x16x32_bf16(av[m], bv[n], acc[m][n], 0,0,0);
    }
  };

  stage(0, 0);
  asm volatile("s_waitcnt vmcnt(0)" ::: "memory");
  __syncthreads();
  int cur=0;
  for(int k0=0;;){
    const int kn = k0+64;
    if(kn<K) stage(cur^1, kn);
    compute(cur);
    asm volatile("s_waitcnt vmcnt(0)" ::: "memory");
    __syncthreads();
    if(kn>=K) break;
    k0=kn; cur^=1;
  }
  #pragma unroll
  for(int m=0;m<4;m++){
    #pragma unroll
    for(int n=0;n<4;n++){
      const int col = n0 + wc*64 + (n<<4) + (l&15);
      float bv_ = 0.f;
      if constexpr(HASB) bv_ = bias[col];
      #pragma unroll
      for(int j=0;j<4;j++){
        const int row = m0 + wr*64 + (m<<4) + ((l>>4)<<2) + j;
        float v = acc[m][n][j] + bv_;
        if constexpr(OBF16) ((ushort*)Cp)[(long)row*N + col] = f2bf(v);
        else ((float*)Cp)[(long)row*N + col] = v;
      }
    }
  }
}

// ---------------- small-tile GEMM template (2-deep reg prefetch) ----------------
// C[M,N] = A[M,K] @ B ; B[k][n] = Bp[sBz*z + n*ldb + k]. K%128==0.
template<bool AF32, bool OBF16, bool HASB>
__global__ __launch_bounds__(256) void k_gemm(const void* __restrict__ Ap,
    const ushort* __restrict__ Bp, void* __restrict__ Cp, const float* __restrict__ bias,
    int M, int N, int K, int lda, int ldb, int ldc, long sAz, long sBz, long sCz)
{
  __shared__ __align__(16) ushort As[4096];
  __shared__ __align__(16) ushort Bs[4096];
  const int tid=threadIdx.x, w=tid>>6, l=tid&63, q4=l>>4;
  const int r=tid>>2, cc=(tid&3)<<4;
  const int m0=blockIdx.y<<6, n0=blockIdx.x<<6;
  const int z=blockIdx.z;
  f4v acc[4];
  #pragma unroll
  for(int i=0;i<4;i++) acc[i]=(f4v){0.f,0.f,0.f,0.f};

  struct PF { float4 f0,f1,f2,f3; s8v u0,u1,b0,b1; };
  PF pA, pB;

  auto loadAB=[&](int k0, PF& p){
    const int gm = m0 + r;
    if constexpr(AF32){
      if(gm < M){
        const float* a = (const float*)Ap + sAz*z + (long)gm*lda + k0 + cc;
        p.f0=*(const float4*)(a); p.f1=*(const float4*)(a+4); p.f2=*(const float4*)(a+8); p.f3=*(const float4*)(a+12);
      } else { p.f0=p.f1=p.f2=p.f3=make_float4(0.f,0.f,0.f,0.f); }
    } else {
      if(gm < M){
        const ushort* a = (const ushort*)Ap + sAz*z + (long)gm*lda + k0 + cc;
        p.u0=*(const s8v*)a; p.u1=*(const s8v*)(a+8);
      } else { p.u0=p.u1=(s8v){0,0,0,0,0,0,0,0}; }
    }
    const ushort* b = Bp + sBz*z + (long)(n0+r)*ldb + k0 + cc;
    p.b0=*(const s8v*)b; p.b1=*(const s8v*)(b+8);
  };
  auto stage=[&](const PF& p){
    s8v a0, a1;
    if constexpr(AF32){
      a0[0]=(short)f2bf(p.f0.x); a0[1]=(short)f2bf(p.f0.y); a0[2]=(short)f2bf(p.f0.z); a0[3]=(short)f2bf(p.f0.w);
      a0[4]=(short)f2bf(p.f1.x); a0[5]=(short)f2bf(p.f1.y); a0[6]=(short)f2bf(p.f1.z); a0[7]=(short)f2bf(p.f1.w);
      a1[0]=(short)f2bf(p.f2.x); a1[1]=(short)f2bf(p.f2.y); a1[2]=(short)f2bf(p.f2.z); a1[3]=(short)f2bf(p.f2.w);
      a1[4]=(short)f2bf(p.f3.x); a1[5]=(short)f2bf(p.f3.y); a1[6]=(short)f2bf(p.f3.z); a1[7]=(short)f2bf(p.f3.w);
    } else { a0=p.u0; a1=p.u1; }
    *(s8v*)&As[swz(r,cc)] = a0; *(s8v*)&As[swz(r,cc+8)] = a1;
    *(s8v*)&Bs[swz(r,cc)] = p.b0; *(s8v*)&Bs[swz(r,cc+8)] = p.b1;
  };
  auto compute=[&](){
    #pragma unroll
    for(int ks=0; ks<64; ks+=32){
      bf8 av = *(const bf8*)&As[swz((w<<4)+(l&15), ks+(q4<<3))];
      #pragma unroll
      for(int nf=0; nf<4; nf++){
        bf8 bv = *(const bf8*)&Bs[swz((nf<<4)+(l&15), ks+(q4<<3))];
        acc[nf] = __builtin_amdgcn_mfma_f32_16x16x32_bf16(av, bv, acc[nf], 0, 0, 0);
      }
    }
  };

  loadAB(0, pA); loadAB(64, pB);
  for(int k0=0; k0<K; k0+=128){
    stage(pA); __syncthreads();
    if(k0+128 < K) loadAB(k0+128, pA);
    compute(); __syncthreads();
    stage(pB); __syncthreads();
    if(k0+192 < K) loadAB(k0+192, pB);
    compute(); __syncthreads();
  }
  #pragma unroll
  for(int nf=0; nf<4; nf++){
    const int col = n0 + (nf<<4) + (l&15);
    float bv = 0.f;
    if constexpr(HASB) bv = bias[col];
    #pragma unroll
    for(int j=0;j<4;j++){
      const int row = m0 + (w<<4) + ((l>>4)<<2) + j;
      if(row < M){
        float v = acc[nf][j] + bv;
        if constexpr(OBF16) ((ushort*)Cp)[sCz*z + (long)row*ldc + col] = f2bf(v);
        else ((float*)Cp)[sCz*z + (long)row*ldc + col] = v;
      }
    }
  }
}

// ---------------- per-step kernels ----------------

// attention partials: 1024 blocks = b*16 + chunk j (32 rows each)
__global__ __launch_bounds__(256) void k_attn(const ushort* __restrict__ esrc,
    const float* __restrict__ q, const float* __restrict__ sbias,
    float* __restrict__ pm, float* __restrict__ pl, float* __restrict__ pctx)
{
  const int b = blockIdx.x>>4, j = blockIdx.x&15;
  const int tid = threadIdx.x, w = tid>>6, l = tid&63;
  __shared__ float ms[4], ls[4];
  __shared__ float ctxs[4][1024];
  float qr[16];
  {
    const float* qp = q + (b<<10) + (l<<4);
    #pragma unroll
    for(int i=0;i<16;i+=4){ float4 v=*(const float4*)(qp+i); qr[i]=v.x; qr[i+1]=v.y; qr[i+2]=v.z; qr[i+3]=v.w; }
  }
  float m = -3.4e38f, lsum = 0.f;
  float cacc[16];
  #pragma unroll
  for(int i=0;i<16;i++) cacc[i]=0.f;
  const int sbase = (j<<5) + w;
  for(int rr=0; rr<8; rr++){
    const int s = sbase + (rr<<2);
    const ushort* ep = esrc + (((long)((b<<9) + s))<<10) + (l<<4);
    s8v e0 = *(const s8v*)ep, e1 = *(const s8v*)(ep+8);
    float ef[16];
    #pragma unroll
    for(int i=0;i<8;i++){ ef[i]=bf2f((ushort)e0[i]); ef[8+i]=bf2f((ushort)e1[i]); }
    float d = 0.f;
    #pragma unroll
    for(int i=0;i<16;i++) d += ef[i]*qr[i];
    d = wred(d);
    d += sbias[(b<<9)+s];
    const float mn = fmaxf(m, d);
    const float sc = __expf(m - mn);
    const float p = __expf(d - mn);
    lsum = lsum*sc + p;
    #pragma unroll
    for(int i=0;i<16;i++) cacc[i] = cacc[i]*sc + p*ef[i];
    m = mn;
  }
  if(l==0){ ms[w]=m; ls[w]=lsum; }
  #pragma unroll
  for(int i=0;i<16;i++) ctxs[w][(l<<4)+i]=cacc[i];
  __syncthreads();
  const float mb = fmaxf(fmaxf(ms[0],ms[1]),fmaxf(ms[2],ms[3]));
  const float w0=__expf(ms[0]-mb), w1=__expf(ms[1]-mb), w2=__expf(ms[2]-mb), w3=__expf(ms[3]-mb);
  const float lb = ls[0]*w0 + ls[1]*w1 + ls[2]*w2 + ls[3]*w3;
  const int jb = (j<<6) + b;
  float* pc = pctx + ((long)jb<<10);
  for(int d0=tid; d0<1024; d0+=256){
    pc[d0] = ctxs[0][d0]*w0 + ctxs[1][d0]*w1 + ctxs[2][d0]*w2 + ctxs[3][d0]*w3;
  }
  if(tid==0){ pm[jb]=mb; pl[jb]=lb; }
}

// combine 16 attn partials -> ctx bf16 into Abuf cols 0:1024 (32 blocks)
__global__ __launch_bounds__(256) void k_combine(const float* __restrict__ pm,
    const float* __restrict__ pl, const float* __restrict__ pctx, ushort* __restrict__ Ab)
{
  const int idx = blockIdx.x*256 + threadIdx.x;   // 0..8191
  const int b = idx>>7, c0 = (idx&127)<<3;
  float mv[16];
  #pragma unroll
  for(int j=0;j<16;j++) mv[j] = pm[(j<<6)+b];
  float M = mv[0];
  #pragma unroll
  for(int j=1;j<16;j++) M = fmaxf(M, mv[j]);
  float e[16]; float den = 0.f;
  #pragma unroll
  for(int j=0;j<16;j++){ e[j] = __expf(mv[j]-M); den += pl[(j<<6)+b]*e[j]; }
  const float inv = 1.f/den;
  float s0=0,s1=0,s2=0,s3=0,s4=0,s5=0,s6=0,s7=0;
  #pragma unroll
  for(int j=0;j<16;j++){
    const float wj = e[j]*inv;
    const float* p = pctx + (((long)((j<<6)+b))<<10) + c0;
    float4 v0=*(const float4*)p, v1=*(const float4*)(p+4);
    s0+=wj*v0.x; s1+=wj*v0.y; s2+=wj*v0.z; s3+=wj*v0.w;
    s4+=wj*v1.x; s5+=wj*v1.y; s6+=wj*v1.z; s7+=wj*v1.w;
  }
  s8v o;
  o[0]=(short)f2bf(s0); o[1]=(short)f2bf(s1); o[2]=(short)f2bf(s2); o[3]=(short)f2bf(s3);
  o[4]=(short)f2bf(s4); o[5]=(short)f2bf(s5); o[6]=(short)f2bf(s6); o[7]=(short)f2bf(s7);
  *(s8v*)&Ab[(b<<11)+c0] = o;
}

// gates GEMM (A=[ctx|h] bf16 [64][2048], B=WcatP permuted [4096][2048]) + LSTM cell
// 64 blocks; block nt covers units j = nt*16 + l15, gates = nf.  (2-deep reg PF)
__global__ __launch_bounds__(256) void k_lstm(const ushort* __restrict__ Abuf,
    const float* __restrict__ cin, const ushort* __restrict__ WcatP,
    const ushort* __restrict__ gpre_t, float* __restrict__ cout,
    ushort* __restrict__ AbOut, ushort* __restrict__ h2t)
{
  __shared__ __align__(16) ushort As[4096];
  __shared__ __align__(16) ushort Bs[4096];
  const int tid=threadIdx.x, w=tid>>6, l=tid&63, q4=l>>4, l15=l&15;
  const int r=tid>>2, cc=(tid&3)<<4;
  const int nt = blockIdx.x;
  f4v acc[4];
  #pragma unroll
  for(int nf=0;nf<4;nf++){
    #pragma unroll
    for(int jj=0;jj<4;jj++){
      const int row = (w<<4) + ((l>>4)<<2) + jj;
      acc[nf][jj] = bf2f(gpre_t[((long)row<<12) + (nt<<6) + (nf<<4) + l15]);
    }
  }
  struct PF { s8v a0,a1,b0,b1; };
  PF pA, pB;
  auto loadAB=[&](int k0, PF& p){
    const ushort* a = Abuf + ((long)r<<11) + k0 + cc;
    p.a0=*(const s8v*)a; p.a1=*(const s8v*)(a+8);
    const ushort* bp = WcatP + ((long)((nt<<6)+r)<<11) + k0 + cc;
    p.b0=*(const s8v*)bp; p.b1=*(const s8v*)(bp+8);
  };
  auto stage=[&](const PF& p){
    *(s8v*)&As[swz(r,cc)] = p.a0; *(s8v*)&As[swz(r,cc+8)] = p.a1;
    *(s8v*)&Bs[swz(r,cc)] = p.b0; *(s8v*)&Bs[swz(r,cc+8)] = p.b1;
  };
  auto compute=[&](){
    #pragma unroll
    for(int ks=0; ks<64; ks+=32){
      bf8 av = *(const bf8*)&As[swz((w<<4)+l15, ks+(q4<<3))];
      #pragma unroll
      for(int nf=0;nf<4;nf++){
        bf8 bv = *(const bf8*)&Bs[swz((nf<<4)+l15, ks+(q4<<3))];
        acc[nf] = __builtin_amdgcn_mfma_f32_16x16x32_bf16(av, bv, acc[nf], 0, 0, 0);
      }
    }
  };
  loadAB(0, pA); loadAB(64, pB);
  for(int k0=0; k0<2048; k0+=128){
    stage(pA); __syncthreads();
    if(k0+128 < 2048) loadAB(k0+128, pA);
    compute(); __syncthreads();
    stage(pB); __syncthreads();
    if(k0+192 < 2048) loadAB(k0+192, pB);
    compute(); __syncthreads();
  }
  #pragma unroll
  for(int jj=0;jj<4;jj++){
    const int row = (w<<4) + ((l>>4)<<2) + jj;
    const int j = (nt<<4) + l15;
    const float iv = acc[0][jj], fv = acc[1][jj], gv = acc[2][jj], ov = acc[3][jj];
    const float cold = cin[(row<<10)+j];
    const float c2 = sigm(fv)*cold + sigm(iv)*tanh_(gv);
    const float h2v = sigm(ov)*tanh_(c2);
    cout[(row<<10)+j] = c2;
    const ushort hb = f2bf(h2v);
    AbOut[(row<<11) + 1024 + j] = hb;
    h2t[(row<<10)+j] = hb;
  }
}

// selected-head LSE + gold logprob per (t,b): grid 640, wave = one (t,b)
__global__ __launch_bounds__(256) void k_loss2(const float* __restrict__ la,
    const float* __restrict__ lcb, const float* __restrict__ ltb,
    const float* __restrict__ ca, const float* __restrict__ cb, const float* __restrict__ ct,
    const int* __restrict__ gold, const int* __restrict__ kindv, float* __restrict__ lossbuf)
{
  const int wv = threadIdx.x>>6, l = threadIdx.x&63;
  const int tb = blockIdx.x*4 + wv;   // 0..2559
  const int t = tb>>6, b = tb&63;
  const int kd = kindv[tb];
  const int gi = gold[tb];
  const float* ptr; const float* cons; int R;
  if(kd==0){ ptr = la + (long)tb*128; cons = ca + (b<<7); R=128; }
  else if(kd==1){ ptr = lcb + (long)b*2560 + t*64; cons = cb + (b<<6); R=64; }
  else { ptr = ltb + (long)b*2560 + t*64; cons = ct + (b<<5); R=32; }
  const int gidx = gi & (R-1);
  const float v  = (l < R) ? (ptr[l] + cons[l]) : -3.4e38f;
  const float v2 = (R==128) ? (ptr[l+64] + cons[l+64]) : -3.4e38f;
  float mx = fmaxf(v, v2);
  #pragma unroll
  for(int off=32; off; off>>=1) mx = fmaxf(mx, __shfl_xor(mx, off, 64));
  float s = ((l<R)?__expf(v-mx):0.f) + ((R==128)?__expf(v2-mx):0.f);
  s = wred(s);
  const float gv = ptr[gidx] + cons[gidx];
  if(l==0) lossbuf[tb] = gv - (mx + __logf(s));
}

__global__ void k_loss_fin(const float* __restrict__ lossbuf, float* __restrict__ out){
  int b = threadIdx.x;
  if(b < 64){
    float s = 0.f;
    for(int t=0;t<40;t++) s += lossbuf[(t<<6)+b];
    out[b] = -s;
  }
}

// ---------------- host ----------------

extern "C" void kernel_launch(void* const* d_in, const int* in_sizes, int n_in,
                              void* d_out, int out_size, void* d_ws, size_t ws_size,
                              hipStream_t stream)
{
  const float *e_src=(const float*)d_in[0], *e_col=(const float*)d_in[1], *e_tab=(const float*)d_in[2];
  const float *h0=(const float*)d_in[3], *c0=(const float*)d_in[4];
  const float *emba=(const float*)d_in[5], *embs=(const float*)d_in[6];
  const float *W_tgt=(const float*)d_in[7], *b_tgt=(const float*)d_in[8];
  const float *W_act=(const float*)d_in[9], *b_act=(const float*)d_in[10];
  const float *W_col=(const float*)d_in[11], *b_col=(const float*)d_in[12];
  const float *W_tab=(const float*)d_in[13], *b_tab=(const float*)d_in[14];
  const float *W_out=(const float*)d_in[15], *b_out=(const float*)d_in[16];
  const float *W_ih=(const float*)d_in[17], *b_ih=(const float*)d_in[18];
  const float *W_hh=(const float*)d_in[19], *b_hh=(const float*)d_in[20];
  const int *smask=(const int*)d_in[21], *cmask=(const int*)d_in[22], *tmask=(const int*)d_in[23];
  const int *amask=(const int*)d_in[24];
  const int *cur=(const int*)d_in[25], *kindp=(const int*)d_in[26], *goldp=(const int*)d_in[27];

  char* wp = (char*)d_ws;
  auto alloc = [&](size_t n)->char*{ char* p = wp; wp += (n + 255) & ~(size_t)255; return p; };
  ushort* esrc_bf = (ushort*)alloc(67108864);
  ushort* WihT    = (ushort*)alloc(16777216);
  ushort* WcatP   = (ushort*)alloc(16777216);
  ushort* WtgtT   = (ushort*)alloc(2097152);
  ushort* BcatT   = (ushort*)alloc(6291456);
  ushort* Woutb   = (ushort*)alloc(2097152);
  float*  U       = (float*) alloc(12582912);   // aliased later by P
  ushort* Ubf     = (ushort*)alloc(6291456);
  ushort* GAt     = (ushort*)alloc(262144);
  ushort* GCt     = (ushort*)alloc(8388608);
  ushort* GTt     = (ushort*)alloc(8388608);    // padded: 64-row slabs per batch
  ushort* gpre    = (ushort*)alloc(20971520);
  float* biasvec  = (float*)alloc(16384);
  float* sbias    = (float*)alloc(131072);
  float* vv       = (float*)alloc(12288);
  float* dbuf     = (float*)alloc(25088);
  float* ca       = (float*)alloc(32768);
  float* cb       = (float*)alloc(16384);
  float* ctb      = (float*)alloc(8192);
  float* pm       = (float*)alloc(4096);
  float* pl       = (float*)alloc(4096);
  float* pctx     = (float*)alloc(4194304);
  ushort* Ab0     = (ushort*)alloc(262144);
  ushort* Ab1     = (ushort*)alloc(262144);
  float* cbuf0    = (float*)alloc(262144);
  float* cbuf1    = (float*)alloc(262144);
  float* qb       = (float*)alloc(262144);
  ushort* h2a     = (ushort*)alloc(5242880);
  float* la       = (float*)alloc(1310720);
  float* lcb      = (float*)alloc(655360);
  float* ltb      = (float*)alloc(655360);
  float* lossbuf  = (float*)alloc(10240);
  ushort* P       = (ushort*)U;                 // alias: P used after U is consumed
  float* out      = (float*)d_out;

  k_cast<<<4096,256,0,stream>>>(e_src, esrc_bf, 8388608L);
  k_cast<<<512,256,0,stream>>>(W_out, Woutb, 262144L);
  k_tr7<<<5120,256,0,stream>>>(W_ih, W_hh, W_tgt, W_col, W_tab, W_act,
                               WihT, WcatP, WtgtT, BcatT);
  k_init<<<256,256,0,stream>>>(h0, c0, b_ih, b_hh, smask, cbuf0, Ab0, biasvec, sbias);

  { dim3 g(24,8); k_gemm128<false,false><<<g,256,0,stream>>>(Woutb, BcatT, U, nullptr, 3072, 1024); }
  k_cast<<<1024,256,0,stream>>>(U, Ubf, 786432L);
  { dim3 g(16,2); k_gemm<true,true,false><<<g,256,0,stream>>>(emba, Ubf+2048, GAt, nullptr,
        128,1024,1024, 1024,3072,1024, 0,0,0); }
  { dim3 g(16,1,64); k_gemm<true,true,false><<<g,256,0,stream>>>(e_col, Ubf, GCt, nullptr,
        64,1024,1024, 1024,3072,1024, 65536,0,65536); }
  { dim3 g(16,1,64); k_gemm<true,true,false><<<g,256,0,stream>>>(e_tab, Ubf+1024, GTt, nullptr,
        32,1024,1024, 1024,3072,1024, 32768,0,65536); }
  k_bias1b<<<768,256,0,stream>>>(b_out, BcatT, b_act, b_col, b_tab, vv);
  k_bias2a<<<1568,256,0,stream>>>(vv, emba, e_col, e_tab, dbuf);
  k_bias2b<<<56,256,0,stream>>>(dbuf, amask, cmask, tmask, ca, cb, ctb);

  k_gatherP<<<2048,256,0,stream>>>(emba, e_col, e_tab, embs, kindp, goldp, cur, P);
  { dim3 g(32,20); k_gemm128<true,true><<<g,256,0,stream>>>(P, WihT, gpre, biasvec, 4096, 2048); }
  { dim3 g(16,1); k_gemm<true,false,true><<<g,256,0,stream>>>(h0, WtgtT, qb, b_tgt,
        64,1024,1024, 1024,1024,1024, 0,0,0); }

  for(int t=0; t<40; t++){
    ushort* Ain  = (t&1) ? Ab1 : Ab0;
    ushort* Aout = (t&1) ? Ab0 : Ab1;
    float* ci = (t&1) ? cbuf1 : cbuf0;
    float* co = (t&1) ? cbuf0 : cbuf1;
    k_attn<<<1024,256,0,stream>>>(esrc_bf, qb, sbias, pm, pl, pctx);
    k_combine<<<32,256,0,stream>>>(pm, pl, pctx, Ain);
    k_lstm<<<64,256,0,stream>>>(Ain, ci, WcatP, gpre + (long)t*262144, co, Aout, h2a + (long)t*65536);
    { dim3 g(16,1); k_gemm<false,false,true><<<g,256,0,stream>>>(Aout + 1024, WtgtT, qb, b_tgt,
          64,1024,1024, 2048,1024,1024, 0,0,0); }
  }

  // loss: logits via MFMA GEMMs, then selected-head LSE
  { dim3 g(1,20); k_gemm128<false,false><<<g,256,0,stream>>>(h2a, GAt, la, nullptr, 128, 1024); }
  { dim3 g(1,1,64); k_gemm<false,false,false><<<g,256,0,stream>>>(h2a, GCt, lcb, nullptr,
        40,64,1024, 65536,1024,64, 1024,65536,2560); }
  { dim3 g(1,1,64); k_gemm<false,false,false><<<g,256,0,stream>>>(h2a, GTt, ltb, nullptr,
        40,64,1024, 65536,1024,64, 1024,65536,2560); }
  k_loss2<<<640,256,0,stream>>>(la, lcb, ltb, ca, cb, ctb, goldp, kindp, lossbuf);
  k_loss_fin<<<1,64,0,stream>>>(lossbuf, out);
}